// Round 1
// 1030.052 us; speedup vs baseline: 1.0313x; 1.0313x over previous
//
#include <hip/hip_runtime.h>
#include <hip/hip_fp16.h>

// ---------------------------------------------------------------------------
// GPN_GCN: GCNConv x2 (LDS-free direct-fragment MFMA GEMMs, 2-deep kc
// pipeline) -> fused MFMA classifier (Wc@We collapsed) -> APPNP(10, f16
// scaled tables, csr-index prefetch) -> log_softmax fused into last step.
// CSR per launch (rank trick: no fill atomics); props are wave-per-node
// half8 gathers, fp32 accumulate.
// ---------------------------------------------------------------------------

struct __align__(16) half8 { __half2 h[4]; };
typedef _Float16 f16x8 __attribute__((ext_vector_type(8)));
typedef float f32x4 __attribute__((ext_vector_type(4)));

__global__ __launch_bounds__(256) void k_init(int* deg, int N) {
    int i = blockIdx.x * 256 + threadIdx.x;
    if (i < N) deg[i] = 1;  // deg=1 accounts for self-loop
}

// atomicAdd return value = rank of edge within its dst.
__global__ __launch_bounds__(256) void k_count(const int* __restrict__ dst,
                                               int* deg, int* __restrict__ rank, int E) {
    int e = blockIdx.x * 256 + threadIdx.x;
    if (e < E) {
        int r = atomicAdd(&deg[dst[e]], 1);
        rank[e] = r - 1;
    }
}

__global__ __launch_bounds__(256) void k_scanA(const int* __restrict__ deg, int* bs, int N) {
    __shared__ int s[256];
    int t = threadIdx.x;
    int i = blockIdx.x * 256 + t;
    int c = (i < N) ? (deg[i] - 1) : 0;
    s[t] = c; __syncthreads();
    for (int o = 128; o > 0; o >>= 1) {
        if (t < o) s[t] += s[t + o];
        __syncthreads();
    }
    if (t == 0) bs[blockIdx.x] = s[0];
}

__global__ __launch_bounds__(512) void k_scanB(int* bs, int NB) {
    __shared__ int s[512];
    int t = threadIdx.x;
    int v = (t < NB) ? bs[t] : 0;
    s[t] = v; __syncthreads();
    for (int o = 1; o < 512; o <<= 1) {
        int u = (t >= o) ? s[t - o] : 0;
        __syncthreads();
        s[t] += u;
        __syncthreads();
    }
    if (t < NB) bs[t] = s[t] - v;  // exclusive
}

__global__ __launch_bounds__(256) void k_scanC(const int* __restrict__ deg, const int* __restrict__ bs,
                                               int* row_ptr, float* dinv, int N) {
    __shared__ int s[256];
    int t = threadIdx.x;
    int i = blockIdx.x * 256 + t;
    int c = (i < N) ? (deg[i] - 1) : 0;
    s[t] = c; __syncthreads();
    for (int o = 1; o < 256; o <<= 1) {
        int u = (t >= o) ? s[t - o] : 0;
        __syncthreads();
        s[t] += u;
        __syncthreads();
    }
    if (i < N) {
        int off = bs[blockIdx.x];
        row_ptr[i] = off + s[t] - c;          // exclusive
        dinv[i] = rsqrtf((float)deg[i]);
        if (i == N - 1) row_ptr[N] = off + s[t];
    }
}

// Atomic-free fill using precomputed ranks.
__global__ __launch_bounds__(256) void k_fill(const int* __restrict__ src, const int* __restrict__ dst,
                                              const int* __restrict__ row_ptr,
                                              const int* __restrict__ rank,
                                              int* __restrict__ csr_src, int E) {
    int e = blockIdx.x * 256 + threadIdx.x;
    if (e < E) csr_src[row_ptr[dst[e]] + rank[e]] = src[e];
}

// Wf = Wc @ We  [128x64], bf = bc @ We + be  [64]. One block.
__global__ __launch_bounds__(256) void k_fuseW(const float* __restrict__ Wc,
                                               const float* __restrict__ bc,
                                               const float* __restrict__ We,
                                               const float* __restrict__ be,
                                               float* __restrict__ Wf,
                                               float* __restrict__ bf) {
    __shared__ float sWe[64 * 64];
    int tid = threadIdx.x;
    for (int i = tid; i < 64 * 64 / 4; i += 256)
        ((float4*)sWe)[i] = ((const float4*)We)[i];
    __syncthreads();
    for (int idx = tid; idx < 128 * 64; idx += 256) {
        int r = idx >> 6, c = idx & 63;
        float s = 0.f;
#pragma unroll 8
        for (int j = 0; j < 64; j++) s += Wc[r * 64 + j] * sWe[j * 64 + c];
        Wf[idx] = s;
    }
    if (tid < 64) {
        float s = be[tid];
#pragma unroll 8
        for (int j = 0; j < 64; j++) s += bc[j] * sWe[j * 64 + tid];
        bf[tid] = s;
    }
}

// Wt[n][k] (f16, [NCOL x K]) = W[k][n] (f32, [K x NCOL]) — B-operand layout.
__global__ __launch_bounds__(256) void k_prepW(const float* __restrict__ W,
                                               __half* __restrict__ Wt, int K, int NCOL) {
    int idx = blockIdx.x * 256 + threadIdx.x;
    if (idx < NCOL * K) {
        int n = idx / K, k = idx % K;
        Wt[idx] = __float2half(W[k * NCOL + n]);
    }
}

// LDS-free MFMA GEMM: Y[M,128](f16) = dinv[row] * (X[M,K] @ W[K,128]).
// 32 rows/block, 2x2 wave grid: wave = 16 rows x 4 col-tiles (64 cols).
// Each lane loads its A-fragment straight from global in MFMA layout
// (lane(m,q) reads 32B of row rw+m: per row the 4 quads cover 128B
// contiguous -> fully coalesced). B is a per-kc 4-fragment window.
// 2-deep software pipeline over kc, fully unrolled (static buffer idx).
// Frag layouts (m89/m120-verified): A[m=lane&15][k=kc*32+quad*8+j],
// B[n=lane&15][k], C/D col=lane&15, row=quad*4+reg.
template <int K, bool IN_F16>
__global__ __launch_bounds__(256) void k_mfma_gemm(const void* __restrict__ Xv,
                                                   const __half* __restrict__ Wt,
                                                   const float* __restrict__ dinv,
                                                   __half* __restrict__ Y, int N) {
    constexpr int NK = K / 32;
    const int tid = threadIdx.x;
    const int wave = tid >> 6, lane = tid & 63;
    const int m = lane & 15, quad = lane >> 4;
    const int rw = (wave & 1) * 16;        // row half
    const int cb = (wave >> 1) * 64;       // col half (4 tiles of 16)
    const int rowBase = blockIdx.x * 32;
    int rowA = rowBase + rw + m;
    if (rowA > N - 1) rowA = N - 1;

    const float*  xf = (const float*)Xv;
    const __half* xh = (const __half*)Xv;
    const long aOff = (long)rowA * K + quad * 8;

    f32x4 d[4];
#pragma unroll
    for (int ct = 0; ct < 4; ++ct) d[ct] = {0.f, 0.f, 0.f, 0.f};

    f16x8 a[2];
    float4 t0[2], t1[2];
    f16x8 b[2][4];

    // prologue: issue kc=0 loads
    if constexpr (IN_F16) {
        a[0] = *(const f16x8*)&xh[aOff];
    } else {
        t0[0] = *(const float4*)&xf[aOff];
        t1[0] = *(const float4*)&xf[aOff + 4];
    }
#pragma unroll
    for (int ct = 0; ct < 4; ++ct)
        b[0][ct] = *(const f16x8*)&Wt[(long)(cb + ct * 16 + m) * K + quad * 8];

#pragma unroll
    for (int kc = 0; kc < NK; ++kc) {
        const int cur = kc & 1, nxt = cur ^ 1;
        if (kc + 1 < NK) {  // prefetch next kc while current MFMAs run
            const int k1 = (kc + 1) * 32;
            if constexpr (IN_F16) {
                a[nxt] = *(const f16x8*)&xh[aOff + k1];
            } else {
                t0[nxt] = *(const float4*)&xf[aOff + k1];
                t1[nxt] = *(const float4*)&xf[aOff + k1 + 4];
            }
#pragma unroll
            for (int ct = 0; ct < 4; ++ct)
                b[nxt][ct] = *(const f16x8*)&Wt[(long)(cb + ct * 16 + m) * K + k1 + quad * 8];
        }
        if constexpr (!IN_F16) {
            f16x8 av;
            av[0] = (_Float16)t0[cur].x; av[1] = (_Float16)t0[cur].y;
            av[2] = (_Float16)t0[cur].z; av[3] = (_Float16)t0[cur].w;
            av[4] = (_Float16)t1[cur].x; av[5] = (_Float16)t1[cur].y;
            av[6] = (_Float16)t1[cur].z; av[7] = (_Float16)t1[cur].w;
            a[cur] = av;
        }
#pragma unroll
        for (int ct = 0; ct < 4; ++ct)
            d[ct] = __builtin_amdgcn_mfma_f32_16x16x32_f16(a[cur], b[cur][ct], d[ct], 0, 0, 0);
    }

#pragma unroll
    for (int ct = 0; ct < 4; ++ct) {
        const int col = cb + ct * 16 + m;
#pragma unroll
        for (int reg = 0; reg < 4; ++reg) {
            const int row = rowBase + rw + quad * 4 + reg;
            if (row < N)
                Y[(long)row * 128 + col] = __float2half(d[ct][reg] * dinv[row]);
        }
    }
}

// Fused classifier via MFMA (f16 input): ev(f32) = relu(H @ Wf + bf);
// evs(f16) = dinv (.) ev. 64 rows/block, wave = 16 rows x 64 cols (4 ct).
__global__ __launch_bounds__(256) void k_cls(const __half* __restrict__ H,
                                             const __half* __restrict__ Wft,
                                             const float* __restrict__ bf,
                                             const float* __restrict__ dinv,
                                             float* __restrict__ ev,
                                             __half* __restrict__ evs, int N) {
    const int tid = threadIdx.x;
    const int wave = tid >> 6, lane = tid & 63;
    const int m = lane & 15, quad = lane >> 4;
    const int rowT = blockIdx.x * 64 + wave * 16;
    int rowA = rowT + m;
    if (rowA > N - 1) rowA = N - 1;
    const long aOff = (long)rowA * 128 + quad * 8;

    f32x4 d[4];
#pragma unroll
    for (int ct = 0; ct < 4; ++ct) d[ct] = {0.f, 0.f, 0.f, 0.f};

    f16x8 a[2], b[2][4];
    a[0] = *(const f16x8*)&H[aOff];
#pragma unroll
    for (int ct = 0; ct < 4; ++ct)
        b[0][ct] = *(const f16x8*)&Wft[(long)(ct * 16 + m) * 128 + quad * 8];

#pragma unroll
    for (int kc = 0; kc < 4; ++kc) {
        const int cur = kc & 1, nxt = cur ^ 1;
        if (kc + 1 < 4) {
            const int k1 = (kc + 1) * 32;
            a[nxt] = *(const f16x8*)&H[aOff + k1];
#pragma unroll
            for (int ct = 0; ct < 4; ++ct)
                b[nxt][ct] = *(const f16x8*)&Wft[(long)(ct * 16 + m) * 128 + k1 + quad * 8];
        }
#pragma unroll
        for (int ct = 0; ct < 4; ++ct)
            d[ct] = __builtin_amdgcn_mfma_f32_16x16x32_f16(a[cur], b[cur][ct], d[ct], 0, 0, 0);
    }

#pragma unroll
    for (int ct = 0; ct < 4; ++ct) {
        const int col = ct * 16 + m;
#pragma unroll
        for (int reg = 0; reg < 4; ++reg) {
            const int row = rowT + quad * 4 + reg;
            if (row < N) {
                float v = fmaxf(d[ct][reg] + bf[col], 0.f);
                ev[(long)row * 64 + col] = v;
                evs[(long)row * 64 + col] = __float2half(v * dinv[row]);
            }
        }
    }
}

// Wave-per-node gather propagation over fp16 scaled table tab = dinv (.) h.
// A = sum_{src in nbr(i)} tab[src] + tab[i]
// MODE 3 (GCN, f16):    out(f16) = relu(di*A + bias)   (unscaled, next input)
// MODE 1 (APPNP inner): out(f16) = 0.9*di^2*A + 0.1*evs[i]   (scaled space)
// MODE 2 (APPNP final): out(f32) = log_softmax(0.9*di*A + 0.1*ev[i])
// csr_src indices for the NEXT group are prefetched before the current
// group's table gathers so the two dependent latencies overlap.
template <int F, int MODE>
__global__ __launch_bounds__(256) void k_prop2(const __half* __restrict__ tab,
                                               const int* __restrict__ row_ptr,
                                               const int* __restrict__ csr_src,
                                               const float* __restrict__ dinv,
                                               const float* __restrict__ bias,
                                               const void* __restrict__ evx,
                                               void* __restrict__ out, int N) {
    constexpr int LPE = F / 8;    // lanes per edge-slot (half8 = 8 feats each)
    constexpr int S = 64 / LPE;   // edge slots per wave
    int wave = threadIdx.x >> 6;
    int lane = threadIdx.x & 63;
    int node = blockIdx.x * 4 + wave;
    if (node >= N) return;
    int slot = lane / LPE;
    int fl = lane % LPE;          // features 8*fl .. 8*fl+7
    const int2 se = *(const int2*)&row_ptr[node];
    int s = se.x, e = se.y;

    float acc[8], accB[8];
#pragma unroll
    for (int q = 0; q < 8; q++) { acc[q] = 0.f; accB[q] = 0.f; }

    int j = s + slot;
    int i0 = 0, i1 = 0;
    if (j < e) i0 = csr_src[j];
    if (j + S < e) i1 = csr_src[j + S];
    while (j + S < e) {
        const int jn = j + 2 * S;
        int n0 = 0, n1 = 0;
        if (jn < e) n0 = csr_src[jn];
        if (jn + S < e) n1 = csr_src[jn + S];
        const half8 a = *(const half8*)&tab[(long)i0 * F + 8 * fl];
        const half8 b = *(const half8*)&tab[(long)i1 * F + 8 * fl];
#pragma unroll
        for (int q = 0; q < 4; q++) {
            float2 fa = __half22float2(a.h[q]);
            float2 fb = __half22float2(b.h[q]);
            acc[2 * q] += fa.x; acc[2 * q + 1] += fa.y;
            accB[2 * q] += fb.x; accB[2 * q + 1] += fb.y;
        }
        i0 = n0; i1 = n1; j = jn;
    }
    if (j < e) {
        const half8 a = *(const half8*)&tab[(long)i0 * F + 8 * fl];
#pragma unroll
        for (int q = 0; q < 4; q++) {
            float2 fa = __half22float2(a.h[q]);
            acc[2 * q] += fa.x; acc[2 * q + 1] += fa.y;
        }
    }
    if (slot == 0) {  // self loop
        const half8 a = *(const half8*)&tab[(long)node * F + 8 * fl];
#pragma unroll
        for (int q = 0; q < 4; q++) {
            float2 fa = __half22float2(a.h[q]);
            acc[2 * q] += fa.x; acc[2 * q + 1] += fa.y;
        }
    }
#pragma unroll
    for (int q = 0; q < 8; q++) acc[q] += accB[q];

#pragma unroll
    for (int off = LPE; off < 64; off <<= 1) {
#pragma unroll
        for (int q = 0; q < 8; q++) acc[q] += __shfl_xor(acc[q], off, 64);
    }

    if (slot == 0) {
        float di = dinv[node];
        if (MODE == 3) {
            const float4 b0 = *(const float4*)&bias[8 * fl];
            const float4 b1 = *(const float4*)&bias[8 * fl + 4];
            half8 ov;
            ov.h[0] = __floats2half2_rn(fmaxf(di * acc[0] + b0.x, 0.f),
                                        fmaxf(di * acc[1] + b0.y, 0.f));
            ov.h[1] = __floats2half2_rn(fmaxf(di * acc[2] + b0.z, 0.f),
                                        fmaxf(di * acc[3] + b0.w, 0.f));
            ov.h[2] = __floats2half2_rn(fmaxf(di * acc[4] + b1.x, 0.f),
                                        fmaxf(di * acc[5] + b1.y, 0.f));
            ov.h[3] = __floats2half2_rn(fmaxf(di * acc[6] + b1.z, 0.f),
                                        fmaxf(di * acc[7] + b1.w, 0.f));
            *(half8*)&((__half*)out)[(long)node * F + 8 * fl] = ov;
        } else if (MODE == 1) {
            float d2 = 0.9f * di * di;
            const half8 eh = *(const half8*)&((const __half*)evx)[(long)node * F + 8 * fl];
            half8 ov;
#pragma unroll
            for (int q = 0; q < 4; q++) {
                float2 ef = __half22float2(eh.h[q]);
                float vx = d2 * acc[2 * q] + 0.1f * ef.x;
                float vy = d2 * acc[2 * q + 1] + 0.1f * ef.y;
                ov.h[q] = __floats2half2_rn(vx, vy);
            }
            *(half8*)&((__half*)out)[(long)node * F + 8 * fl] = ov;
        } else {
            // final APPNP step fused with log_softmax (F==64: lanes 0..7
            // of each wave hold the full 64-class row, 8 classes each)
            float d1 = 0.9f * di;
            const float* ef = (const float*)evx + (long)node * F + 8 * fl;
            const float4 e0 = *(const float4*)ef;
            const float4 e1 = *(const float4*)(ef + 4);
            float v[8];
            v[0] = d1 * acc[0] + 0.1f * e0.x;
            v[1] = d1 * acc[1] + 0.1f * e0.y;
            v[2] = d1 * acc[2] + 0.1f * e0.z;
            v[3] = d1 * acc[3] + 0.1f * e0.w;
            v[4] = d1 * acc[4] + 0.1f * e1.x;
            v[5] = d1 * acc[5] + 0.1f * e1.y;
            v[6] = d1 * acc[6] + 0.1f * e1.z;
            v[7] = d1 * acc[7] + 0.1f * e1.w;
            float m = v[0];
#pragma unroll
            for (int q = 1; q < 8; q++) m = fmaxf(m, v[q]);
#pragma unroll
            for (int off = 1; off < LPE; off <<= 1) m = fmaxf(m, __shfl_xor(m, off, 64));
            float ssum = 0.f;
#pragma unroll
            for (int q = 0; q < 8; q++) ssum += __expf(v[q] - m);
#pragma unroll
            for (int off = 1; off < LPE; off <<= 1) ssum += __shfl_xor(ssum, off, 64);
            float lse = m + __logf(ssum);
            float* o = (float*)out + (long)node * F + 8 * fl;
            float4 v0, v1;
            v0.x = v[0] - lse; v0.y = v[1] - lse; v0.z = v[2] - lse; v0.w = v[3] - lse;
            v1.x = v[4] - lse; v1.y = v[5] - lse; v1.z = v[6] - lse; v1.w = v[7] - lse;
            *(float4*)o = v0;
            *(float4*)(o + 4) = v1;
        }
    }
}

extern "C" void kernel_launch(void* const* d_in, const int* in_sizes, int n_in,
                              void* d_out, int out_size, void* d_ws, size_t ws_size,
                              hipStream_t stream) {
    const float* x  = (const float*)d_in[0];
    const int* edges = (const int*)d_in[1];
    const float* W1 = (const float*)d_in[2];
    const float* b1 = (const float*)d_in[3];
    const float* W2 = (const float*)d_in[4];
    const float* b2 = (const float*)d_in[5];
    const float* Wc = (const float*)d_in[6];
    const float* bc = (const float*)d_in[7];
    const float* We = (const float*)d_in[8];
    const float* be = (const float*)d_in[9];

    const int N = in_sizes[0] / 256;   // 100000
    const int E = in_sizes[1] / 2;     // 1600000
    const int* esrc = edges;
    const int* edst = edges + E;

    char* ws = (char*)d_ws;
    size_t off = 0;
    auto alloc = [&](size_t bytes) -> void* {
        void* p = ws + off;
        off += (bytes + 255) & ~(size_t)255;
        return p;
    };
    int*    deg     = (int*)alloc((size_t)N * 4);
    int*    row_ptr = (int*)alloc((size_t)(N + 1) * 4);
    float*  dinv    = (float*)alloc((size_t)N * 4);
    int*    bs      = (int*)alloc(4096 * 4);
    int*    rank    = (int*)alloc((size_t)E * 4);
    int*    csr_src = (int*)alloc((size_t)E * 4);
    __half* P       = (__half*)alloc((size_t)N * 128 * 2);  // f16 table A
    __half* Q16     = (__half*)alloc((size_t)N * 128 * 2);  // f16 table B
    __half* zA      = (__half*)alloc((size_t)N * 64 * 2);
    __half* zB      = (__half*)alloc((size_t)N * 64 * 2);
    __half* evs     = (__half*)alloc((size_t)N * 64 * 2);
    float*  Wf      = (float*)alloc(128 * 64 * 4);
    float*  bf      = (float*)alloc(64 * 4);
    __half* W1t     = (__half*)alloc(128 * 256 * 2);
    __half* W2t     = (__half*)alloc(128 * 128 * 2);
    __half* Wft     = (__half*)alloc(64 * 128 * 2);
    float*  ev      = (float*)d_out;  // f32 ev lives in d_out until final step

    const int nbN = (N + 255) / 256;
    const int nbE = (E + 255) / 256;
    const int nbP = (N + 3) / 4;      // wave-per-node kernels
    const int nbG = (N + 31) / 32;    // MFMA GEMM blocks (32 rows each)
    const int nbC = (N + 63) / 64;    // classifier blocks (64 rows each)

    // --- CSR build + weight prep (fuseW/prepW independent of CSR) ---
    k_init<<<nbN, 256, 0, stream>>>(deg, N);
    k_count<<<nbE, 256, 0, stream>>>(edst, deg, rank, E);
    k_fuseW<<<1, 256, 0, stream>>>(Wc, bc, We, be, Wf, bf);
    k_prepW<<<(128 * 256 + 255) / 256, 256, 0, stream>>>(W1, W1t, 256, 128);
    k_prepW<<<(128 * 128 + 255) / 256, 256, 0, stream>>>(W2, W2t, 128, 128);
    k_prepW<<<(64 * 128 + 255) / 256, 256, 0, stream>>>(Wf, Wft, 128, 64);
    k_scanA<<<nbN, 256, 0, stream>>>(deg, bs, N);
    k_scanB<<<1, 512, 0, stream>>>(bs, nbN);
    k_scanC<<<nbN, 256, 0, stream>>>(deg, bs, row_ptr, dinv, N);
    k_fill<<<nbE, 256, 0, stream>>>(esrc, edst, row_ptr, rank, csr_src, E);

    // --- GCN layer 1: P = f16(dinv * x@W1) via MFMA; Q16 = f16 relu prop ---
    k_mfma_gemm<256, false><<<nbG, 256, 0, stream>>>(x, W1t, dinv, P, N);
    k_prop2<128, 3><<<nbP, 256, 0, stream>>>(P, row_ptr, csr_src, dinv, b1, nullptr, Q16, N);

    // --- GCN layer 2: P = f16(dinv * Q16@W2) via MFMA; Q16 = f16 relu prop ---
    k_mfma_gemm<128, true><<<nbG, 256, 0, stream>>>(Q16, W2t, dinv, P, N);
    k_prop2<128, 3><<<nbP, 256, 0, stream>>>(P, row_ptr, csr_src, dinv, b2, nullptr, Q16, N);

    // --- fused classifier (MFMA): ev (f32, d_out) + evs (f16 scaled) ---
    k_cls<<<nbC, 256, 0, stream>>>(Q16, Wft, bf, dinv, ev, evs, N);

    // --- APPNP: 9 scaled f16 iterations + final step fused w/ log_softmax ---
    const __half* zin = evs;
    __half* zout;
    for (int it = 0; it < 9; ++it) {
        zout = (it % 2 == 0) ? zA : zB;
        k_prop2<64, 1><<<nbP, 256, 0, stream>>>(zin, row_ptr, csr_src, dinv, nullptr, evs, zout, N);
        zin = zout;
    }
    // final: reads zA(f16) + ev(f32,d_out), writes log_softmax rows to d_out
    k_prop2<64, 2><<<nbP, 256, 0, stream>>>(zin, row_ptr, csr_src, dinv, nullptr, ev, (float*)d_out, N);
}

// Round 2
// 972.270 us; speedup vs baseline: 1.0926x; 1.0594x over previous
//
#include <hip/hip_runtime.h>
#include <hip/hip_fp16.h>

// ---------------------------------------------------------------------------
// GPN_GCN: GCNConv x2 (MFMA GEMMs: B staged once per block in LDS in
// fragment-major layout, A streamed direct-from-global in fragment layout,
// 4-kc chunked issue) -> fused MFMA classifier (Wc@We collapsed) ->
// APPNP(10, f16 scaled tables, csr-index prefetch) -> log_softmax fused
// into last step. CSR per launch (rank trick: no fill atomics); props are
// wave-per-node half8 gathers, fp32 accumulate.
// ---------------------------------------------------------------------------

struct __align__(16) half8 { __half2 h[4]; };
typedef _Float16 f16x8 __attribute__((ext_vector_type(8)));
typedef float f32x4 __attribute__((ext_vector_type(4)));

__device__ __forceinline__ f16x8 cvt8(const float4& a, const float4& b) {
    f16x8 r;
    r[0] = (_Float16)a.x; r[1] = (_Float16)a.y; r[2] = (_Float16)a.z; r[3] = (_Float16)a.w;
    r[4] = (_Float16)b.x; r[5] = (_Float16)b.y; r[6] = (_Float16)b.z; r[7] = (_Float16)b.w;
    return r;
}

__global__ __launch_bounds__(256) void k_init(int* deg, int N) {
    int i = blockIdx.x * 256 + threadIdx.x;
    if (i < N) deg[i] = 1;  // deg=1 accounts for self-loop
}

// atomicAdd return value = rank of edge within its dst.
__global__ __launch_bounds__(256) void k_count(const int* __restrict__ dst,
                                               int* deg, int* __restrict__ rank, int E) {
    int e = blockIdx.x * 256 + threadIdx.x;
    if (e < E) {
        int r = atomicAdd(&deg[dst[e]], 1);
        rank[e] = r - 1;
    }
}

__global__ __launch_bounds__(256) void k_scanA(const int* __restrict__ deg, int* bs, int N) {
    __shared__ int s[256];
    int t = threadIdx.x;
    int i = blockIdx.x * 256 + t;
    int c = (i < N) ? (deg[i] - 1) : 0;
    s[t] = c; __syncthreads();
    for (int o = 128; o > 0; o >>= 1) {
        if (t < o) s[t] += s[t + o];
        __syncthreads();
    }
    if (t == 0) bs[blockIdx.x] = s[0];
}

__global__ __launch_bounds__(512) void k_scanB(int* bs, int NB) {
    __shared__ int s[512];
    int t = threadIdx.x;
    int v = (t < NB) ? bs[t] : 0;
    s[t] = v; __syncthreads();
    for (int o = 1; o < 512; o <<= 1) {
        int u = (t >= o) ? s[t - o] : 0;
        __syncthreads();
        s[t] += u;
        __syncthreads();
    }
    if (t < NB) bs[t] = s[t] - v;  // exclusive
}

__global__ __launch_bounds__(256) void k_scanC(const int* __restrict__ deg, const int* __restrict__ bs,
                                               int* row_ptr, float* dinv, int N) {
    __shared__ int s[256];
    int t = threadIdx.x;
    int i = blockIdx.x * 256 + t;
    int c = (i < N) ? (deg[i] - 1) : 0;
    s[t] = c; __syncthreads();
    for (int o = 1; o < 256; o <<= 1) {
        int u = (t >= o) ? s[t - o] : 0;
        __syncthreads();
        s[t] += u;
        __syncthreads();
    }
    if (i < N) {
        int off = bs[blockIdx.x];
        row_ptr[i] = off + s[t] - c;          // exclusive
        dinv[i] = rsqrtf((float)deg[i]);
        if (i == N - 1) row_ptr[N] = off + s[t];
    }
}

// Atomic-free fill using precomputed ranks.
__global__ __launch_bounds__(256) void k_fill(const int* __restrict__ src, const int* __restrict__ dst,
                                              const int* __restrict__ row_ptr,
                                              const int* __restrict__ rank,
                                              int* __restrict__ csr_src, int E) {
    int e = blockIdx.x * 256 + threadIdx.x;
    if (e < E) csr_src[row_ptr[dst[e]] + rank[e]] = src[e];
}

// Wf = Wc @ We  [128x64], bf = bc @ We + be  [64]. One block.
__global__ __launch_bounds__(256) void k_fuseW(const float* __restrict__ Wc,
                                               const float* __restrict__ bc,
                                               const float* __restrict__ We,
                                               const float* __restrict__ be,
                                               float* __restrict__ Wf,
                                               float* __restrict__ bf) {
    __shared__ float sWe[64 * 64];
    int tid = threadIdx.x;
    for (int i = tid; i < 64 * 64 / 4; i += 256)
        ((float4*)sWe)[i] = ((const float4*)We)[i];
    __syncthreads();
    for (int idx = tid; idx < 128 * 64; idx += 256) {
        int r = idx >> 6, c = idx & 63;
        float s = 0.f;
#pragma unroll 8
        for (int j = 0; j < 64; j++) s += Wc[r * 64 + j] * sWe[j * 64 + c];
        Wf[idx] = s;
    }
    if (tid < 64) {
        float s = be[tid];
#pragma unroll 8
        for (int j = 0; j < 64; j++) s += bc[j] * sWe[j * 64 + tid];
        bf[tid] = s;
    }
}

// Fragment-major B prep: Wt[((kc*4+quad)*NCOL + n)*8 + j] = f16(W[k][n]),
// k = kc*32 + quad*8 + j. Staging to LDS is then a pure linear copy and the
// per-fragment LDS read is 16 consecutive 16B lanes (conflict-free b128).
__global__ __launch_bounds__(256) void k_prepW2(const float* __restrict__ W,
                                                __half* __restrict__ Wt, int K, int NCOL) {
    int idx = blockIdx.x * 256 + threadIdx.x;
    if (idx >= K * NCOL) return;
    int j = idx & 7;
    int n = (idx >> 3) % NCOL;
    int qk = idx / (8 * NCOL);
    int quad = qk & 3, kc = qk >> 2;
    int k = kc * 32 + quad * 8 + j;
    Wt[idx] = __float2half(W[k * NCOL + n]);
}

// MFMA GEMM: Y[M,128](f16) = dinv[row] * (X[M,K] @ W[K,128]).
// 512 threads = 8 waves, 128 rows/block; wave = 16 rows x 128 cols (8 ct).
// B (fragment-major) staged once into LDS (two-phase reg staging); per-kc
// B reads are contiguous conflict-free ds_read_b128. A streamed from global
// in MFMA fragment layout, issued in 4-kc chunks (8 dwordx4/lane in flight).
// Frag layouts (m89/m120-verified): A[m=lane&15][k=kc*32+quad*8+j],
// B[n=lane&15][k], C/D col=lane&15, row=quad*4+reg.
template <int K, bool IN_F16>
__global__ __launch_bounds__(512, 4) void k_gemm(const void* __restrict__ Xv,
                                                 const __half* __restrict__ Wtf,
                                                 const float* __restrict__ dinv,
                                                 __half* __restrict__ Y, int N) {
    constexpr int NK = K / 32;
    constexpr int ITER = K / 32;  // staging sweeps: K*128*2 / (512*16)
    __shared__ __align__(16) __half sB[K * 128];

    const int tid = threadIdx.x;
    const int wv = tid >> 6, ln = tid & 63;
    const int m = ln & 15, quad = ln >> 4;
    const int rowBase = blockIdx.x * 128 + wv * 16;
    int rowA = rowBase + m;
    if (rowA > N - 1) rowA = N - 1;

    const float*  xf = (const float*)Xv;
    const __half* xh = (const __half*)Xv;
    const long aOff = (long)rowA * K + quad * 8;

    // --- issue A chunk0 (all independent, before staging) ---
    f16x8 a8[4];
    float4 t0[4], t1[4];
    if constexpr (IN_F16) {
#pragma unroll
        for (int kc = 0; kc < NK; ++kc)
            a8[kc] = *(const f16x8*)&xh[aOff + kc * 32];
    } else {
#pragma unroll
        for (int c = 0; c < 4; ++c) {
            t0[c] = *(const float4*)&xf[aOff + c * 32];
            t1[c] = *(const float4*)&xf[aOff + c * 32 + 4];
        }
    }

    // --- stage B into LDS (two-phase: all loads in flight, then writes) ---
    {
        f16x8 tb[ITER];
        const f16x8* g = (const f16x8*)Wtf;
#pragma unroll
        for (int i = 0; i < ITER; ++i) tb[i] = g[(i * 8 + wv) * 64 + ln];
        f16x8* l = (f16x8*)sB;
#pragma unroll
        for (int i = 0; i < ITER; ++i) l[(i * 8 + wv) * 64 + ln] = tb[i];
    }
    __syncthreads();

    if constexpr (!IN_F16) {
        // convert chunk0, then issue chunk1 into the freed t-registers
#pragma unroll
        for (int c = 0; c < 4; ++c) a8[c] = cvt8(t0[c], t1[c]);
#pragma unroll
        for (int c = 0; c < 4; ++c) {
            t0[c] = *(const float4*)&xf[aOff + (c + 4) * 32];
            t1[c] = *(const float4*)&xf[aOff + (c + 4) * 32 + 4];
        }
    }

    f32x4 d[8];
#pragma unroll
    for (int ct = 0; ct < 8; ++ct) d[ct] = {0.f, 0.f, 0.f, 0.f};

#pragma unroll
    for (int h = 0; h < NK / 4; ++h) {
        if constexpr (!IN_F16) {
            if (h == 1) {
#pragma unroll
                for (int c = 0; c < 4; ++c) a8[c] = cvt8(t0[c], t1[c]);
            }
        }
#pragma unroll
        for (int kq = 0; kq < 4; ++kq) {
            const int kc = h * 4 + kq;
            const f16x8 a = a8[IN_F16 ? kc : kq];
            const __half* bb = &sB[(size_t)(kc * 4 + quad) * 128 * 8];
#pragma unroll
            for (int ct = 0; ct < 8; ++ct) {
                const f16x8 b = *(const f16x8*)&bb[(ct * 16 + m) * 8];
                d[ct] = __builtin_amdgcn_mfma_f32_16x16x32_f16(a, b, d[ct], 0, 0, 0);
            }
        }
    }

#pragma unroll
    for (int ct = 0; ct < 8; ++ct) {
        const int col = ct * 16 + m;
#pragma unroll
        for (int reg = 0; reg < 4; ++reg) {
            const int row = rowBase + quad * 4 + reg;
            if (row < N)
                Y[(long)row * 128 + col] = __float2half(d[ct][reg] * dinv[row]);
        }
    }
}

// Fused classifier via MFMA (f16 input): ev(f32) = relu(H @ Wf + bf);
// evs(f16) = dinv (.) ev. Same structure as k_gemm: B (16KB) in LDS,
// 512 threads, 128 rows/block, wave = 16 rows x 64 cols (4 ct), K=128.
__global__ __launch_bounds__(512, 4) void k_cls(const __half* __restrict__ H,
                                                const __half* __restrict__ Wtf,
                                                const float* __restrict__ bf,
                                                const float* __restrict__ dinv,
                                                float* __restrict__ ev,
                                                __half* __restrict__ evs, int N) {
    __shared__ __align__(16) __half sB[128 * 64];
    const int tid = threadIdx.x;
    const int wv = tid >> 6, ln = tid & 63;
    const int m = ln & 15, quad = ln >> 4;
    const int rowBase = blockIdx.x * 128 + wv * 16;
    int rowA = rowBase + m;
    if (rowA > N - 1) rowA = N - 1;
    const long aOff = (long)rowA * 128 + quad * 8;

    f16x8 a8[4];
#pragma unroll
    for (int kc = 0; kc < 4; ++kc)
        a8[kc] = *(const f16x8*)&H[aOff + kc * 32];

    {
        f16x8 tb[2];
        const f16x8* g = (const f16x8*)Wtf;
#pragma unroll
        for (int i = 0; i < 2; ++i) tb[i] = g[(i * 8 + wv) * 64 + ln];
        f16x8* l = (f16x8*)sB;
#pragma unroll
        for (int i = 0; i < 2; ++i) l[(i * 8 + wv) * 64 + ln] = tb[i];
    }
    __syncthreads();

    f32x4 d[4];
#pragma unroll
    for (int ct = 0; ct < 4; ++ct) d[ct] = {0.f, 0.f, 0.f, 0.f};

#pragma unroll
    for (int kc = 0; kc < 4; ++kc) {
        const __half* bb = &sB[(size_t)(kc * 4 + quad) * 64 * 8];
#pragma unroll
        for (int ct = 0; ct < 4; ++ct) {
            const f16x8 b = *(const f16x8*)&bb[(ct * 16 + m) * 8];
            d[ct] = __builtin_amdgcn_mfma_f32_16x16x32_f16(a8[kc], b, d[ct], 0, 0, 0);
        }
    }

#pragma unroll
    for (int ct = 0; ct < 4; ++ct) {
        const int col = ct * 16 + m;
#pragma unroll
        for (int reg = 0; reg < 4; ++reg) {
            const int row = rowBase + quad * 4 + reg;
            if (row < N) {
                float v = fmaxf(d[ct][reg] + bf[col], 0.f);
                ev[(long)row * 64 + col] = v;
                evs[(long)row * 64 + col] = __float2half(v * dinv[row]);
            }
        }
    }
}

// Wave-per-node gather propagation over fp16 scaled table tab = dinv (.) h.
// A = sum_{src in nbr(i)} tab[src] + tab[i]
// MODE 3 (GCN, f16):    out(f16) = relu(di*A + bias)   (unscaled, next input)
// MODE 1 (APPNP inner): out(f16) = 0.9*di^2*A + 0.1*evs[i]   (scaled space)
// MODE 2 (APPNP final): out(f32) = log_softmax(0.9*di*A + 0.1*ev[i])
// csr_src indices for the NEXT group are prefetched before the current
// group's table gathers so the two dependent latencies overlap.
template <int F, int MODE>
__global__ __launch_bounds__(256) void k_prop2(const __half* __restrict__ tab,
                                               const int* __restrict__ row_ptr,
                                               const int* __restrict__ csr_src,
                                               const float* __restrict__ dinv,
                                               const float* __restrict__ bias,
                                               const void* __restrict__ evx,
                                               void* __restrict__ out, int N) {
    constexpr int LPE = F / 8;    // lanes per edge-slot (half8 = 8 feats each)
    constexpr int S = 64 / LPE;   // edge slots per wave
    int wave = threadIdx.x >> 6;
    int lane = threadIdx.x & 63;
    int node = blockIdx.x * 4 + wave;
    if (node >= N) return;
    int slot = lane / LPE;
    int fl = lane % LPE;          // features 8*fl .. 8*fl+7
    const int2 se = *(const int2*)&row_ptr[node];
    int s = se.x, e = se.y;

    float acc[8], accB[8];
#pragma unroll
    for (int q = 0; q < 8; q++) { acc[q] = 0.f; accB[q] = 0.f; }

    int j = s + slot;
    int i0 = 0, i1 = 0;
    if (j < e) i0 = csr_src[j];
    if (j + S < e) i1 = csr_src[j + S];
    while (j + S < e) {
        const int jn = j + 2 * S;
        int n0 = 0, n1 = 0;
        if (jn < e) n0 = csr_src[jn];
        if (jn + S < e) n1 = csr_src[jn + S];
        const half8 a = *(const half8*)&tab[(long)i0 * F + 8 * fl];
        const half8 b = *(const half8*)&tab[(long)i1 * F + 8 * fl];
#pragma unroll
        for (int q = 0; q < 4; q++) {
            float2 fa = __half22float2(a.h[q]);
            float2 fb = __half22float2(b.h[q]);
            acc[2 * q] += fa.x; acc[2 * q + 1] += fa.y;
            accB[2 * q] += fb.x; accB[2 * q + 1] += fb.y;
        }
        i0 = n0; i1 = n1; j = jn;
    }
    if (j < e) {
        const half8 a = *(const half8*)&tab[(long)i0 * F + 8 * fl];
#pragma unroll
        for (int q = 0; q < 4; q++) {
            float2 fa = __half22float2(a.h[q]);
            acc[2 * q] += fa.x; acc[2 * q + 1] += fa.y;
        }
    }
    if (slot == 0) {  // self loop
        const half8 a = *(const half8*)&tab[(long)node * F + 8 * fl];
#pragma unroll
        for (int q = 0; q < 4; q++) {
            float2 fa = __half22float2(a.h[q]);
            acc[2 * q] += fa.x; acc[2 * q + 1] += fa.y;
        }
    }
#pragma unroll
    for (int q = 0; q < 8; q++) acc[q] += accB[q];

#pragma unroll
    for (int off = LPE; off < 64; off <<= 1) {
#pragma unroll
        for (int q = 0; q < 8; q++) acc[q] += __shfl_xor(acc[q], off, 64);
    }

    if (slot == 0) {
        float di = dinv[node];
        if (MODE == 3) {
            const float4 b0 = *(const float4*)&bias[8 * fl];
            const float4 b1 = *(const float4*)&bias[8 * fl + 4];
            half8 ov;
            ov.h[0] = __floats2half2_rn(fmaxf(di * acc[0] + b0.x, 0.f),
                                        fmaxf(di * acc[1] + b0.y, 0.f));
            ov.h[1] = __floats2half2_rn(fmaxf(di * acc[2] + b0.z, 0.f),
                                        fmaxf(di * acc[3] + b0.w, 0.f));
            ov.h[2] = __floats2half2_rn(fmaxf(di * acc[4] + b1.x, 0.f),
                                        fmaxf(di * acc[5] + b1.y, 0.f));
            ov.h[3] = __floats2half2_rn(fmaxf(di * acc[6] + b1.z, 0.f),
                                        fmaxf(di * acc[7] + b1.w, 0.f));
            *(half8*)&((__half*)out)[(long)node * F + 8 * fl] = ov;
        } else if (MODE == 1) {
            float d2 = 0.9f * di * di;
            const half8 eh = *(const half8*)&((const __half*)evx)[(long)node * F + 8 * fl];
            half8 ov;
#pragma unroll
            for (int q = 0; q < 4; q++) {
                float2 ef = __half22float2(eh.h[q]);
                float vx = d2 * acc[2 * q] + 0.1f * ef.x;
                float vy = d2 * acc[2 * q + 1] + 0.1f * ef.y;
                ov.h[q] = __floats2half2_rn(vx, vy);
            }
            *(half8*)&((__half*)out)[(long)node * F + 8 * fl] = ov;
        } else {
            // final APPNP step fused with log_softmax (F==64: lanes 0..7
            // of each wave hold the full 64-class row, 8 classes each)
            float d1 = 0.9f * di;
            const float* ef = (const float*)evx + (long)node * F + 8 * fl;
            const float4 e0 = *(const float4*)ef;
            const float4 e1 = *(const float4*)(ef + 4);
            float v[8];
            v[0] = d1 * acc[0] + 0.1f * e0.x;
            v[1] = d1 * acc[1] + 0.1f * e0.y;
            v[2] = d1 * acc[2] + 0.1f * e0.z;
            v[3] = d1 * acc[3] + 0.1f * e0.w;
            v[4] = d1 * acc[4] + 0.1f * e1.x;
            v[5] = d1 * acc[5] + 0.1f * e1.y;
            v[6] = d1 * acc[6] + 0.1f * e1.z;
            v[7] = d1 * acc[7] + 0.1f * e1.w;
            float m = v[0];
#pragma unroll
            for (int q = 1; q < 8; q++) m = fmaxf(m, v[q]);
#pragma unroll
            for (int off = 1; off < LPE; off <<= 1) m = fmaxf(m, __shfl_xor(m, off, 64));
            float ssum = 0.f;
#pragma unroll
            for (int q = 0; q < 8; q++) ssum += __expf(v[q] - m);
#pragma unroll
            for (int off = 1; off < LPE; off <<= 1) ssum += __shfl_xor(ssum, off, 64);
            float lse = m + __logf(ssum);
            float* o = (float*)out + (long)node * F + 8 * fl;
            float4 v0, v1;
            v0.x = v[0] - lse; v0.y = v[1] - lse; v0.z = v[2] - lse; v0.w = v[3] - lse;
            v1.x = v[4] - lse; v1.y = v[5] - lse; v1.z = v[6] - lse; v1.w = v[7] - lse;
            *(float4*)o = v0;
            *(float4*)(o + 4) = v1;
        }
    }
}

extern "C" void kernel_launch(void* const* d_in, const int* in_sizes, int n_in,
                              void* d_out, int out_size, void* d_ws, size_t ws_size,
                              hipStream_t stream) {
    const float* x  = (const float*)d_in[0];
    const int* edges = (const int*)d_in[1];
    const float* W1 = (const float*)d_in[2];
    const float* b1 = (const float*)d_in[3];
    const float* W2 = (const float*)d_in[4];
    const float* b2 = (const float*)d_in[5];
    const float* Wc = (const float*)d_in[6];
    const float* bc = (const float*)d_in[7];
    const float* We = (const float*)d_in[8];
    const float* be = (const float*)d_in[9];

    const int N = in_sizes[0] / 256;   // 100000
    const int E = in_sizes[1] / 2;     // 1600000
    const int* esrc = edges;
    const int* edst = edges + E;

    char* ws = (char*)d_ws;
    size_t off = 0;
    auto alloc = [&](size_t bytes) -> void* {
        void* p = ws + off;
        off += (bytes + 255) & ~(size_t)255;
        return p;
    };
    int*    deg     = (int*)alloc((size_t)N * 4);
    int*    row_ptr = (int*)alloc((size_t)(N + 1) * 4);
    float*  dinv    = (float*)alloc((size_t)N * 4);
    int*    bs      = (int*)alloc(4096 * 4);
    int*    rank    = (int*)alloc((size_t)E * 4);
    int*    csr_src = (int*)alloc((size_t)E * 4);
    __half* P       = (__half*)alloc((size_t)N * 128 * 2);  // f16 table A
    __half* Q16     = (__half*)alloc((size_t)N * 128 * 2);  // f16 table B
    __half* zA      = (__half*)alloc((size_t)N * 64 * 2);
    __half* zB      = (__half*)alloc((size_t)N * 64 * 2);
    __half* evs     = (__half*)alloc((size_t)N * 64 * 2);
    float*  Wf      = (float*)alloc(128 * 64 * 4);
    float*  bf      = (float*)alloc(64 * 4);
    __half* W1t     = (__half*)alloc(128 * 256 * 2);  // fragment-major
    __half* W2t     = (__half*)alloc(128 * 128 * 2);  // fragment-major
    __half* Wft     = (__half*)alloc(64 * 128 * 2);   // fragment-major
    float*  ev      = (float*)d_out;  // f32 ev lives in d_out until final step

    const int nbN = (N + 255) / 256;
    const int nbE = (E + 255) / 256;
    const int nbP = (N + 3) / 4;        // wave-per-node kernels
    const int TG  = (N + 127) / 128;    // GEMM/cls blocks (128 rows each)

    // --- CSR build + weight prep (fuseW/prepW independent of CSR) ---
    k_init<<<nbN, 256, 0, stream>>>(deg, N);
    k_count<<<nbE, 256, 0, stream>>>(edst, deg, rank, E);
    k_fuseW<<<1, 256, 0, stream>>>(Wc, bc, We, be, Wf, bf);
    k_prepW2<<<(256 * 128 + 255) / 256, 256, 0, stream>>>(W1, W1t, 256, 128);
    k_prepW2<<<(128 * 128 + 255) / 256, 256, 0, stream>>>(W2, W2t, 128, 128);
    k_prepW2<<<(128 * 64 + 255) / 256, 256, 0, stream>>>(Wf, Wft, 128, 64);
    k_scanA<<<nbN, 256, 0, stream>>>(deg, bs, N);
    k_scanB<<<1, 512, 0, stream>>>(bs, nbN);
    k_scanC<<<nbN, 256, 0, stream>>>(deg, bs, row_ptr, dinv, N);
    k_fill<<<nbE, 256, 0, stream>>>(esrc, edst, row_ptr, rank, csr_src, E);

    // --- GCN layer 1: P = f16(dinv * x@W1) via MFMA; Q16 = f16 relu prop ---
    k_gemm<256, false><<<TG, 512, 0, stream>>>(x, W1t, dinv, P, N);
    k_prop2<128, 3><<<nbP, 256, 0, stream>>>(P, row_ptr, csr_src, dinv, b1, nullptr, Q16, N);

    // --- GCN layer 2: P = f16(dinv * Q16@W2) via MFMA; Q16 = f16 relu prop ---
    k_gemm<128, true><<<TG, 512, 0, stream>>>(Q16, W2t, dinv, P, N);
    k_prop2<128, 3><<<nbP, 256, 0, stream>>>(P, row_ptr, csr_src, dinv, b2, nullptr, Q16, N);

    // --- fused classifier (MFMA): ev (f32, d_out) + evs (f16 scaled) ---
    k_cls<<<TG, 512, 0, stream>>>(Q16, Wft, bf, dinv, ev, evs, N);

    // --- APPNP: 9 scaled f16 iterations + final step fused w/ log_softmax ---
    const __half* zin = evs;
    __half* zout;
    for (int it = 0; it < 9; ++it) {
        zout = (it % 2 == 0) ? zA : zB;
        k_prop2<64, 1><<<nbP, 256, 0, stream>>>(zin, row_ptr, csr_src, dinv, nullptr, evs, zout, N);
        zin = zout;
    }
    // final: reads zA(f16) + ev(f32,d_out), writes log_softmax rows to d_out
    k_prop2<64, 2><<<nbP, 256, 0, stream>>>(zin, row_ptr, csr_src, dinv, nullptr, ev, (float*)d_out, N);
}

// Round 3
// 941.279 us; speedup vs baseline: 1.1286x; 1.0329x over previous
//
#include <hip/hip_runtime.h>
#include <hip/hip_fp16.h>

// ---------------------------------------------------------------------------
// GPN_GCN: fat kernel (GEMM1 MFMA + edge-count atomics overlapped; GEMM1
// writes unscaled H, prop1 applies per-edge dinv) -> GCN layer2 MFMA ->
// fused MFMA classifier (Wc@We collapsed) -> APPNP(10, f16 scaled tables)
// -> log_softmax fused into last step. CSR per launch (rank trick); props
// are wave-per-node half8 gathers, fp32 accumulate.
// ---------------------------------------------------------------------------

struct __align__(16) half8 { __half2 h[4]; };
typedef _Float16 f16x8 __attribute__((ext_vector_type(8)));
typedef float f32x4 __attribute__((ext_vector_type(4)));

__device__ __forceinline__ f16x8 cvt8(const float4& a, const float4& b) {
    f16x8 r;
    r[0] = (_Float16)a.x; r[1] = (_Float16)a.y; r[2] = (_Float16)a.z; r[3] = (_Float16)a.w;
    r[4] = (_Float16)b.x; r[5] = (_Float16)b.y; r[6] = (_Float16)b.z; r[7] = (_Float16)b.w;
    return r;
}

__global__ __launch_bounds__(256) void k_scanA(const int* __restrict__ deg, int* bs, int N) {
    __shared__ int s[256];
    int t = threadIdx.x;
    int i = blockIdx.x * 256 + t;
    int c = (i < N) ? deg[i] : 0;
    s[t] = c; __syncthreads();
    for (int o = 128; o > 0; o >>= 1) {
        if (t < o) s[t] += s[t + o];
        __syncthreads();
    }
    if (t == 0) bs[blockIdx.x] = s[0];
}

__global__ __launch_bounds__(512) void k_scanB(int* bs, int NB) {
    __shared__ int s[512];
    int t = threadIdx.x;
    int v = (t < NB) ? bs[t] : 0;
    s[t] = v; __syncthreads();
    for (int o = 1; o < 512; o <<= 1) {
        int u = (t >= o) ? s[t - o] : 0;
        __syncthreads();
        s[t] += u;
        __syncthreads();
    }
    if (t < NB) bs[t] = s[t] - v;  // exclusive
}

__global__ __launch_bounds__(256) void k_scanC(const int* __restrict__ deg, const int* __restrict__ bs,
                                               int* row_ptr, float* dinv, int N) {
    __shared__ int s[256];
    int t = threadIdx.x;
    int i = blockIdx.x * 256 + t;
    int c = (i < N) ? deg[i] : 0;
    s[t] = c; __syncthreads();
    for (int o = 1; o < 256; o <<= 1) {
        int u = (t >= o) ? s[t - o] : 0;
        __syncthreads();
        s[t] += u;
        __syncthreads();
    }
    if (i < N) {
        int off = bs[blockIdx.x];
        row_ptr[i] = off + s[t] - c;          // exclusive (edges only)
        dinv[i] = rsqrtf((float)(deg[i] + 1));  // +1 = self loop
        if (i == N - 1) row_ptr[N] = off + s[t];
    }
}

// Atomic-free fill using precomputed ranks.
__global__ __launch_bounds__(256) void k_fill(const int* __restrict__ src, const int* __restrict__ dst,
                                              const int* __restrict__ row_ptr,
                                              const int* __restrict__ rank,
                                              int* __restrict__ csr_src, int E) {
    int e = blockIdx.x * 256 + threadIdx.x;
    if (e < E) csr_src[row_ptr[dst[e]] + rank[e]] = src[e];
}

// One merged prep kernel: blocks [0,128) -> W1t frag-major; [128,192) ->
// W2t frag-major; block 192 -> Wft = f16 frag-major (Wc@We), bf = bc@We+be.
// Fragment-major layout: Wt[((kc*4+quad)*NCOL + n)*8 + j], k=kc*32+quad*8+j.
__global__ __launch_bounds__(256) void k_prep(const float* __restrict__ W1,
                                              const float* __restrict__ W2,
                                              const float* __restrict__ Wc,
                                              const float* __restrict__ bc,
                                              const float* __restrict__ We,
                                              const float* __restrict__ be,
                                              __half* __restrict__ W1t,
                                              __half* __restrict__ W2t,
                                              __half* __restrict__ Wft,
                                              float* __restrict__ bf) {
    __shared__ float sWe[64 * 64];
    const int b = blockIdx.x, tid = threadIdx.x;
    if (b < 128) {           // W1t: K=256, NCOL=128 (32768 elems)
        int idx = b * 256 + tid;
        int j = idx & 7, n = (idx >> 3) & 127, qk = idx >> 10;
        int quad = qk & 3, kc = qk >> 2;
        int k = kc * 32 + quad * 8 + j;
        W1t[idx] = __float2half(W1[k * 128 + n]);
    } else if (b < 192) {    // W2t: K=128, NCOL=128 (16384 elems)
        int idx = (b - 128) * 256 + tid;
        int j = idx & 7, n = (idx >> 3) & 127, qk = idx >> 10;
        int quad = qk & 3, kc = qk >> 2;
        int k = kc * 32 + quad * 8 + j;
        W2t[idx] = __float2half(W2[k * 128 + n]);
    } else {                 // fuse: Wft (f16 frag-major) + bf
        for (int i = tid; i < 64 * 64 / 4; i += 256)
            ((float4*)sWe)[i] = ((const float4*)We)[i];
        __syncthreads();
        for (int idx = tid; idx < 128 * 64; idx += 256) {
            int r = idx >> 6, c = idx & 63;
            float s = 0.f;
#pragma unroll 8
            for (int j = 0; j < 64; j++) s += Wc[r * 64 + j] * sWe[j * 64 + c];
            int kc = r >> 5, quad = (r >> 3) & 3, jj = r & 7;
            Wft[(((kc * 4 + quad) * 64) + c) * 8 + jj] = __float2half(s);
        }
        if (tid < 64) {
            float s = be[tid];
#pragma unroll 8
            for (int j = 0; j < 64; j++) s += bc[j] * sWe[j * 64 + tid];
            bf[tid] = s;
        }
    }
}

// MFMA GEMM (+ optional fused edge-count): Y[M,128](f16) = X[M,K] @ W[K,128]
// (scaled by dinv[row] unless COUNT). Blocks >= TG (COUNT only) run the
// atomic degree/rank counting — zero data dependency on the GEMM, so the
// atomic-bound work hides under the GEMM's BW-bound phase.
// 512 threads, 128 rows/block; wave = 16 rows x 128 cols (8 ct).
// B (fragment-major) staged once into LDS; A streamed from global in MFMA
// fragment layout (m89/m120-verified layouts).
template <int K, bool IN_F16, bool COUNT>
__global__ __launch_bounds__(512, 4) void k_gemm(const void* __restrict__ Xv,
                                                 const __half* __restrict__ Wtf,
                                                 const float* __restrict__ dinv,
                                                 __half* __restrict__ Y, int N,
                                                 const int* __restrict__ dst,
                                                 int* __restrict__ deg,
                                                 int* __restrict__ rank,
                                                 int E, int TG) {
    if constexpr (COUNT) {
        if (blockIdx.x >= TG) {
            int e = (blockIdx.x - TG) * 512 + threadIdx.x;
            if (e < E) {
                int r = atomicAdd(&deg[dst[e]], 1);
                rank[e] = r;
            }
            return;
        }
    }
    constexpr int NK = K / 32;
    constexpr int ITER = K / 32;  // staging sweeps: K*128*2 / (512*16)
    __shared__ __align__(16) __half sB[K * 128];

    const int tid = threadIdx.x;
    const int wv = tid >> 6, ln = tid & 63;
    const int m = ln & 15, quad = ln >> 4;
    const int rowBase = blockIdx.x * 128 + wv * 16;
    int rowA = rowBase + m;
    if (rowA > N - 1) rowA = N - 1;

    const float*  xf = (const float*)Xv;
    const __half* xh = (const __half*)Xv;
    const long aOff = (long)rowA * K + quad * 8;

    // --- issue A chunk0 (all independent, before staging) ---
    f16x8 a8[4];
    float4 t0[4], t1[4];
    if constexpr (IN_F16) {
#pragma unroll
        for (int kc = 0; kc < NK; ++kc)
            a8[kc] = *(const f16x8*)&xh[aOff + kc * 32];
    } else {
#pragma unroll
        for (int c = 0; c < 4; ++c) {
            t0[c] = *(const float4*)&xf[aOff + c * 32];
            t1[c] = *(const float4*)&xf[aOff + c * 32 + 4];
        }
    }

    // --- stage B into LDS (two-phase: all loads in flight, then writes) ---
    {
        f16x8 tb[ITER];
        const f16x8* g = (const f16x8*)Wtf;
#pragma unroll
        for (int i = 0; i < ITER; ++i) tb[i] = g[(i * 8 + wv) * 64 + ln];
        f16x8* l = (f16x8*)sB;
#pragma unroll
        for (int i = 0; i < ITER; ++i) l[(i * 8 + wv) * 64 + ln] = tb[i];
    }
    __syncthreads();

    if constexpr (!IN_F16) {
        // convert chunk0, then issue chunk1 into the freed t-registers
#pragma unroll
        for (int c = 0; c < 4; ++c) a8[c] = cvt8(t0[c], t1[c]);
#pragma unroll
        for (int c = 0; c < 4; ++c) {
            t0[c] = *(const float4*)&xf[aOff + (c + 4) * 32];
            t1[c] = *(const float4*)&xf[aOff + (c + 4) * 32 + 4];
        }
    }

    f32x4 d[8];
#pragma unroll
    for (int ct = 0; ct < 8; ++ct) d[ct] = {0.f, 0.f, 0.f, 0.f};

#pragma unroll
    for (int h = 0; h < NK / 4; ++h) {
        if constexpr (!IN_F16) {
            if (h == 1) {
#pragma unroll
                for (int c = 0; c < 4; ++c) a8[c] = cvt8(t0[c], t1[c]);
            }
        }
#pragma unroll
        for (int kq = 0; kq < 4; ++kq) {
            const int kc = h * 4 + kq;
            const f16x8 a = a8[IN_F16 ? kc : kq];
            const __half* bb = &sB[(size_t)(kc * 4 + quad) * 128 * 8];
#pragma unroll
            for (int ct = 0; ct < 8; ++ct) {
                const f16x8 b = *(const f16x8*)&bb[(ct * 16 + m) * 8];
                d[ct] = __builtin_amdgcn_mfma_f32_16x16x32_f16(a, b, d[ct], 0, 0, 0);
            }
        }
    }

#pragma unroll
    for (int ct = 0; ct < 8; ++ct) {
        const int col = ct * 16 + m;
#pragma unroll
        for (int reg = 0; reg < 4; ++reg) {
            const int row = rowBase + quad * 4 + reg;
            if (row < N) {
                if constexpr (COUNT)
                    Y[(long)row * 128 + col] = __float2half(d[ct][reg]);
                else
                    Y[(long)row * 128 + col] = __float2half(d[ct][reg] * dinv[row]);
            }
        }
    }
}

// Fused classifier via MFMA (f16 input): ev(f32) = relu(H @ Wf + bf);
// evs(f16) = dinv (.) ev. B (16KB) in LDS, 512 threads, 128 rows/block,
// wave = 16 rows x 64 cols (4 ct), K=128.
__global__ __launch_bounds__(512, 4) void k_cls(const __half* __restrict__ H,
                                                const __half* __restrict__ Wtf,
                                                const float* __restrict__ bf,
                                                const float* __restrict__ dinv,
                                                float* __restrict__ ev,
                                                __half* __restrict__ evs, int N) {
    __shared__ __align__(16) __half sB[128 * 64];
    const int tid = threadIdx.x;
    const int wv = tid >> 6, ln = tid & 63;
    const int m = ln & 15, quad = ln >> 4;
    const int rowBase = blockIdx.x * 128 + wv * 16;
    int rowA = rowBase + m;
    if (rowA > N - 1) rowA = N - 1;
    const long aOff = (long)rowA * 128 + quad * 8;

    f16x8 a8[4];
#pragma unroll
    for (int kc = 0; kc < 4; ++kc)
        a8[kc] = *(const f16x8*)&H[aOff + kc * 32];

    {
        f16x8 tb[2];
        const f16x8* g = (const f16x8*)Wtf;
#pragma unroll
        for (int i = 0; i < 2; ++i) tb[i] = g[(i * 8 + wv) * 64 + ln];
        f16x8* l = (f16x8*)sB;
#pragma unroll
        for (int i = 0; i < 2; ++i) l[(i * 8 + wv) * 64 + ln] = tb[i];
    }
    __syncthreads();

    f32x4 d[4];
#pragma unroll
    for (int ct = 0; ct < 4; ++ct) d[ct] = {0.f, 0.f, 0.f, 0.f};

#pragma unroll
    for (int kc = 0; kc < 4; ++kc) {
        const __half* bb = &sB[(size_t)(kc * 4 + quad) * 64 * 8];
#pragma unroll
        for (int ct = 0; ct < 4; ++ct) {
            const f16x8 b = *(const f16x8*)&bb[(ct * 16 + m) * 8];
            d[ct] = __builtin_amdgcn_mfma_f32_16x16x32_f16(a8[kc], b, d[ct], 0, 0, 0);
        }
    }

#pragma unroll
    for (int ct = 0; ct < 4; ++ct) {
        const int col = ct * 16 + m;
#pragma unroll
        for (int reg = 0; reg < 4; ++reg) {
            const int row = rowBase + quad * 4 + reg;
            if (row < N) {
                float v = fmaxf(d[ct][reg] + bf[col], 0.f);
                ev[(long)row * 64 + col] = v;
                evs[(long)row * 64 + col] = __float2half(v * dinv[row]);
            }
        }
    }
}

// Wave-per-node gather propagation over fp16 table.
// MODE 4 (GCN, f16, unscaled tab): out = relu(di * (sum dinv[src]*tab[src]
//                                   + dinv[i]*tab[i]) + bias)
// MODE 3 (GCN, f16, prescaled tab): out = relu(di*A + bias)
// MODE 1 (APPNP inner): out(f16) = 0.9*di^2*A + 0.1*evs[i]   (scaled space)
// MODE 2 (APPNP final): out(f32) = log_softmax(0.9*di*A + 0.1*ev[i])
// csr_src indices for the NEXT group are prefetched before the current
// group's table gathers so the two dependent latencies overlap.
template <int F, int MODE>
__global__ __launch_bounds__(256) void k_prop2(const __half* __restrict__ tab,
                                               const int* __restrict__ row_ptr,
                                               const int* __restrict__ csr_src,
                                               const float* __restrict__ dinv,
                                               const float* __restrict__ bias,
                                               const void* __restrict__ evx,
                                               void* __restrict__ out, int N) {
    constexpr int LPE = F / 8;    // lanes per edge-slot (half8 = 8 feats each)
    constexpr int S = 64 / LPE;   // edge slots per wave
    int wave = threadIdx.x >> 6;
    int lane = threadIdx.x & 63;
    int node = blockIdx.x * 4 + wave;
    if (node >= N) return;
    int slot = lane / LPE;
    int fl = lane % LPE;          // features 8*fl .. 8*fl+7
    const int2 se = *(const int2*)&row_ptr[node];
    int s = se.x, e = se.y;

    float acc[8], accB[8];
#pragma unroll
    for (int q = 0; q < 8; q++) { acc[q] = 0.f; accB[q] = 0.f; }

    int j = s + slot;
    int i0 = 0, i1 = 0;
    if (j < e) i0 = csr_src[j];
    if (j + S < e) i1 = csr_src[j + S];
    while (j + S < e) {
        const int jn = j + 2 * S;
        int n0 = 0, n1 = 0;
        if (jn < e) n0 = csr_src[jn];
        if (jn + S < e) n1 = csr_src[jn + S];
        const half8 a = *(const half8*)&tab[(long)i0 * F + 8 * fl];
        const half8 b = *(const half8*)&tab[(long)i1 * F + 8 * fl];
        if (MODE == 4) {
            float da = dinv[i0], db = dinv[i1];
#pragma unroll
            for (int q = 0; q < 4; q++) {
                float2 fa = __half22float2(a.h[q]);
                float2 fb = __half22float2(b.h[q]);
                acc[2 * q] += da * fa.x; acc[2 * q + 1] += da * fa.y;
                accB[2 * q] += db * fb.x; accB[2 * q + 1] += db * fb.y;
            }
        } else {
#pragma unroll
            for (int q = 0; q < 4; q++) {
                float2 fa = __half22float2(a.h[q]);
                float2 fb = __half22float2(b.h[q]);
                acc[2 * q] += fa.x; acc[2 * q + 1] += fa.y;
                accB[2 * q] += fb.x; accB[2 * q + 1] += fb.y;
            }
        }
        i0 = n0; i1 = n1; j = jn;
    }
    if (j < e) {
        const half8 a = *(const half8*)&tab[(long)i0 * F + 8 * fl];
        if (MODE == 4) {
            float da = dinv[i0];
#pragma unroll
            for (int q = 0; q < 4; q++) {
                float2 fa = __half22float2(a.h[q]);
                acc[2 * q] += da * fa.x; acc[2 * q + 1] += da * fa.y;
            }
        } else {
#pragma unroll
            for (int q = 0; q < 4; q++) {
                float2 fa = __half22float2(a.h[q]);
                acc[2 * q] += fa.x; acc[2 * q + 1] += fa.y;
            }
        }
    }
    if (slot == 0) {  // self loop
        const half8 a = *(const half8*)&tab[(long)node * F + 8 * fl];
        float ds = (MODE == 4) ? dinv[node] : 1.f;
#pragma unroll
        for (int q = 0; q < 4; q++) {
            float2 fa = __half22float2(a.h[q]);
            acc[2 * q] += ds * fa.x; acc[2 * q + 1] += ds * fa.y;
        }
    }
#pragma unroll
    for (int q = 0; q < 8; q++) acc[q] += accB[q];

#pragma unroll
    for (int off = LPE; off < 64; off <<= 1) {
#pragma unroll
        for (int q = 0; q < 8; q++) acc[q] += __shfl_xor(acc[q], off, 64);
    }

    if (slot == 0) {
        float di = dinv[node];
        if (MODE == 3 || MODE == 4) {
            const float4 b0 = *(const float4*)&bias[8 * fl];
            const float4 b1 = *(const float4*)&bias[8 * fl + 4];
            half8 ov;
            ov.h[0] = __floats2half2_rn(fmaxf(di * acc[0] + b0.x, 0.f),
                                        fmaxf(di * acc[1] + b0.y, 0.f));
            ov.h[1] = __floats2half2_rn(fmaxf(di * acc[2] + b0.z, 0.f),
                                        fmaxf(di * acc[3] + b0.w, 0.f));
            ov.h[2] = __floats2half2_rn(fmaxf(di * acc[4] + b1.x, 0.f),
                                        fmaxf(di * acc[5] + b1.y, 0.f));
            ov.h[3] = __floats2half2_rn(fmaxf(di * acc[6] + b1.z, 0.f),
                                        fmaxf(di * acc[7] + b1.w, 0.f));
            *(half8*)&((__half*)out)[(long)node * F + 8 * fl] = ov;
        } else if (MODE == 1) {
            float d2 = 0.9f * di * di;
            const half8 eh = *(const half8*)&((const __half*)evx)[(long)node * F + 8 * fl];
            half8 ov;
#pragma unroll
            for (int q = 0; q < 4; q++) {
                float2 ef = __half22float2(eh.h[q]);
                float vx = d2 * acc[2 * q] + 0.1f * ef.x;
                float vy = d2 * acc[2 * q + 1] + 0.1f * ef.y;
                ov.h[q] = __floats2half2_rn(vx, vy);
            }
            *(half8*)&((__half*)out)[(long)node * F + 8 * fl] = ov;
        } else {
            // final APPNP step fused with log_softmax (F==64: lanes 0..7
            // of each wave hold the full 64-class row, 8 classes each)
            float d1 = 0.9f * di;
            const float* ef = (const float*)evx + (long)node * F + 8 * fl;
            const float4 e0 = *(const float4*)ef;
            const float4 e1 = *(const float4*)(ef + 4);
            float v[8];
            v[0] = d1 * acc[0] + 0.1f * e0.x;
            v[1] = d1 * acc[1] + 0.1f * e0.y;
            v[2] = d1 * acc[2] + 0.1f * e0.z;
            v[3] = d1 * acc[3] + 0.1f * e0.w;
            v[4] = d1 * acc[4] + 0.1f * e1.x;
            v[5] = d1 * acc[5] + 0.1f * e1.y;
            v[6] = d1 * acc[6] + 0.1f * e1.z;
            v[7] = d1 * acc[7] + 0.1f * e1.w;
            float m = v[0];
#pragma unroll
            for (int q = 1; q < 8; q++) m = fmaxf(m, v[q]);
#pragma unroll
            for (int off = 1; off < LPE; off <<= 1) m = fmaxf(m, __shfl_xor(m, off, 64));
            float ssum = 0.f;
#pragma unroll
            for (int q = 0; q < 8; q++) ssum += __expf(v[q] - m);
#pragma unroll
            for (int off = 1; off < LPE; off <<= 1) ssum += __shfl_xor(ssum, off, 64);
            float lse = m + __logf(ssum);
            float* o = (float*)out + (long)node * F + 8 * fl;
            float4 v0, v1;
            v0.x = v[0] - lse; v0.y = v[1] - lse; v0.z = v[2] - lse; v0.w = v[3] - lse;
            v1.x = v[4] - lse; v1.y = v[5] - lse; v1.z = v[6] - lse; v1.w = v[7] - lse;
            *(float4*)o = v0;
            *(float4*)(o + 4) = v1;
        }
    }
}

extern "C" void kernel_launch(void* const* d_in, const int* in_sizes, int n_in,
                              void* d_out, int out_size, void* d_ws, size_t ws_size,
                              hipStream_t stream) {
    const float* x  = (const float*)d_in[0];
    const int* edges = (const int*)d_in[1];
    const float* W1 = (const float*)d_in[2];
    const float* b1 = (const float*)d_in[3];
    const float* W2 = (const float*)d_in[4];
    const float* b2 = (const float*)d_in[5];
    const float* Wc = (const float*)d_in[6];
    const float* bc = (const float*)d_in[7];
    const float* We = (const float*)d_in[8];
    const float* be = (const float*)d_in[9];

    const int N = in_sizes[0] / 256;   // 100000
    const int E = in_sizes[1] / 2;     // 1600000
    const int* esrc = edges;
    const int* edst = edges + E;

    char* ws = (char*)d_ws;
    size_t off = 0;
    auto alloc = [&](size_t bytes) -> void* {
        void* p = ws + off;
        off += (bytes + 255) & ~(size_t)255;
        return p;
    };
    int*    deg     = (int*)alloc((size_t)N * 4);
    int*    row_ptr = (int*)alloc((size_t)(N + 1) * 4);
    float*  dinv    = (float*)alloc((size_t)N * 4);
    int*    bs      = (int*)alloc(4096 * 4);
    int*    rank    = (int*)alloc((size_t)E * 4);
    int*    csr_src = (int*)alloc((size_t)E * 4);
    __half* P       = (__half*)alloc((size_t)N * 128 * 2);  // f16 table A
    __half* Q16     = (__half*)alloc((size_t)N * 128 * 2);  // f16 table B
    __half* zA      = (__half*)alloc((size_t)N * 64 * 2);
    __half* zB      = (__half*)alloc((size_t)N * 64 * 2);
    __half* evs     = (__half*)alloc((size_t)N * 64 * 2);
    float*  bf      = (float*)alloc(64 * 4);
    __half* W1t     = (__half*)alloc(128 * 256 * 2);  // fragment-major
    __half* W2t     = (__half*)alloc(128 * 128 * 2);  // fragment-major
    __half* Wft     = (__half*)alloc(64 * 128 * 2);   // fragment-major
    float*  ev      = (float*)d_out;  // f32 ev lives in d_out until final step

    const int nbN = (N + 255) / 256;
    const int nbE = (E + 255) / 256;
    const int nbP = (N + 3) / 4;        // wave-per-node kernels
    const int TG  = (N + 127) / 128;    // GEMM/cls blocks (128 rows each)
    const int CB  = (E + 511) / 512;    // count blocks in fat kernel

    // --- prep + fat kernel: GEMM1 (unscaled) overlapped with edge count ---
    hipMemsetAsync(deg, 0, (size_t)N * 4, stream);
    k_prep<<<193, 256, 0, stream>>>(W1, W2, Wc, bc, We, be, W1t, W2t, Wft, bf);
    k_gemm<256, false, true><<<TG + CB, 512, 0, stream>>>(x, W1t, nullptr, P, N,
                                                          edst, deg, rank, E, TG);

    // --- CSR build ---
    k_scanA<<<nbN, 256, 0, stream>>>(deg, bs, N);
    k_scanB<<<1, 512, 0, stream>>>(bs, nbN);
    k_scanC<<<nbN, 256, 0, stream>>>(deg, bs, row_ptr, dinv, N);
    k_fill<<<nbE, 256, 0, stream>>>(esrc, edst, row_ptr, rank, csr_src, E);

    // --- GCN layer 1 prop (per-edge dinv: MODE 4, P unscaled) ---
    k_prop2<128, 4><<<nbP, 256, 0, stream>>>(P, row_ptr, csr_src, dinv, b1, nullptr, Q16, N);

    // --- GCN layer 2: P = f16(dinv * Q16@W2) via MFMA; Q16 = f16 relu prop ---
    k_gemm<128, true, false><<<TG, 512, 0, stream>>>(Q16, W2t, dinv, P, N,
                                                     nullptr, nullptr, nullptr, 0, TG);
    k_prop2<128, 3><<<nbP, 256, 0, stream>>>(P, row_ptr, csr_src, dinv, b2, nullptr, Q16, N);

    // --- fused classifier (MFMA): ev (f32, d_out) + evs (f16 scaled) ---
    k_cls<<<TG, 512, 0, stream>>>(Q16, Wft, bf, dinv, ev, evs, N);

    // --- APPNP: 9 scaled f16 iterations + final step fused w/ log_softmax ---
    const __half* zin = evs;
    __half* zout;
    for (int it = 0; it < 9; ++it) {
        zout = (it % 2 == 0) ? zA : zB;
        k_prop2<64, 1><<<nbP, 256, 0, stream>>>(zin, row_ptr, csr_src, dinv, nullptr, evs, zout, N);
        zin = zout;
    }
    // final: reads zA(f16) + ev(f32,d_out), writes log_softmax rows to d_out
    k_prop2<64, 2><<<nbP, 256, 0, stream>>>(zin, row_ptr, csr_src, dinv, nullptr, ev, (float*)d_out, N);
}

// Round 4
// 929.654 us; speedup vs baseline: 1.1427x; 1.0125x over previous
//
#include <hip/hip_runtime.h>
#include <hip/hip_fp16.h>

// ---------------------------------------------------------------------------
// GPN_GCN: fat kernel (GEMM1 MFMA with edge-count atomics fused INTO each
// GEMM block: issue-early / commit-late, so atomic latency+throughput hide
// under the GEMM's staging/MFMA/BW phases) -> GCN layer2 MFMA -> fused MFMA
// classifier (Wc@We collapsed) -> APPNP(10, f16 scaled tables) ->
// log_softmax fused into last step. CSR per launch (rank trick); props are
// wave-per-node half8 gathers, fp32 accumulate.
// ---------------------------------------------------------------------------

struct __align__(16) half8 { __half2 h[4]; };
typedef _Float16 f16x8 __attribute__((ext_vector_type(8)));
typedef float f32x4 __attribute__((ext_vector_type(4)));

__device__ __forceinline__ f16x8 cvt8(const float4& a, const float4& b) {
    f16x8 r;
    r[0] = (_Float16)a.x; r[1] = (_Float16)a.y; r[2] = (_Float16)a.z; r[3] = (_Float16)a.w;
    r[4] = (_Float16)b.x; r[5] = (_Float16)b.y; r[6] = (_Float16)b.z; r[7] = (_Float16)b.w;
    return r;
}

__global__ __launch_bounds__(256) void k_scanA(const int* __restrict__ deg, int* bs, int N) {
    __shared__ int s[256];
    int t = threadIdx.x;
    int i = blockIdx.x * 256 + t;
    int c = (i < N) ? deg[i] : 0;
    s[t] = c; __syncthreads();
    for (int o = 128; o > 0; o >>= 1) {
        if (t < o) s[t] += s[t + o];
        __syncthreads();
    }
    if (t == 0) bs[blockIdx.x] = s[0];
}

__global__ __launch_bounds__(512) void k_scanB(int* bs, int NB) {
    __shared__ int s[512];
    int t = threadIdx.x;
    int v = (t < NB) ? bs[t] : 0;
    s[t] = v; __syncthreads();
    for (int o = 1; o < 512; o <<= 1) {
        int u = (t >= o) ? s[t - o] : 0;
        __syncthreads();
        s[t] += u;
        __syncthreads();
    }
    if (t < NB) bs[t] = s[t] - v;  // exclusive
}

__global__ __launch_bounds__(256) void k_scanC(const int* __restrict__ deg, const int* __restrict__ bs,
                                               int* row_ptr, float* dinv, int N) {
    __shared__ int s[256];
    int t = threadIdx.x;
    int i = blockIdx.x * 256 + t;
    int c = (i < N) ? deg[i] : 0;
    s[t] = c; __syncthreads();
    for (int o = 1; o < 256; o <<= 1) {
        int u = (t >= o) ? s[t - o] : 0;
        __syncthreads();
        s[t] += u;
        __syncthreads();
    }
    if (i < N) {
        int off = bs[blockIdx.x];
        row_ptr[i] = off + s[t] - c;          // exclusive (edges only)
        dinv[i] = rsqrtf((float)(deg[i] + 1));  // +1 = self loop
        if (i == N - 1) row_ptr[N] = off + s[t];
    }
}

// Atomic-free fill using precomputed ranks.
__global__ __launch_bounds__(256) void k_fill(const int* __restrict__ src, const int* __restrict__ dst,
                                              const int* __restrict__ row_ptr,
                                              const int* __restrict__ rank,
                                              int* __restrict__ csr_src, int E) {
    int e = blockIdx.x * 256 + threadIdx.x;
    if (e < E) csr_src[row_ptr[dst[e]] + rank[e]] = src[e];
}

// One merged prep kernel: blocks [0,128) -> W1t frag-major; [128,192) ->
// W2t frag-major; block 192 -> Wft = f16 frag-major (Wc@We), bf = bc@We+be.
// Fragment-major layout: Wt[((kc*4+quad)*NCOL + n)*8 + j], k=kc*32+quad*8+j.
__global__ __launch_bounds__(256) void k_prep(const float* __restrict__ W1,
                                              const float* __restrict__ W2,
                                              const float* __restrict__ Wc,
                                              const float* __restrict__ bc,
                                              const float* __restrict__ We,
                                              const float* __restrict__ be,
                                              __half* __restrict__ W1t,
                                              __half* __restrict__ W2t,
                                              __half* __restrict__ Wft,
                                              float* __restrict__ bf) {
    __shared__ float sWe[64 * 64];
    const int b = blockIdx.x, tid = threadIdx.x;
    if (b < 128) {           // W1t: K=256, NCOL=128 (32768 elems)
        int idx = b * 256 + tid;
        int j = idx & 7, n = (idx >> 3) & 127, qk = idx >> 10;
        int quad = qk & 3, kc = qk >> 2;
        int k = kc * 32 + quad * 8 + j;
        W1t[idx] = __float2half(W1[k * 128 + n]);
    } else if (b < 192) {    // W2t: K=128, NCOL=128 (16384 elems)
        int idx = (b - 128) * 256 + tid;
        int j = idx & 7, n = (idx >> 3) & 127, qk = idx >> 10;
        int quad = qk & 3, kc = qk >> 2;
        int k = kc * 32 + quad * 8 + j;
        W2t[idx] = __float2half(W2[k * 128 + n]);
    } else {                 // fuse: Wft (f16 frag-major) + bf
        for (int i = tid; i < 64 * 64 / 4; i += 256)
            ((float4*)sWe)[i] = ((const float4*)We)[i];
        __syncthreads();
        for (int idx = tid; idx < 128 * 64; idx += 256) {
            int r = idx >> 6, c = idx & 63;
            float s = 0.f;
#pragma unroll 8
            for (int j = 0; j < 64; j++) s += Wc[r * 64 + j] * sWe[j * 64 + c];
            int kc = r >> 5, quad = (r >> 3) & 3, jj = r & 7;
            Wft[(((kc * 4 + quad) * 64) + c) * 8 + jj] = __float2half(s);
        }
        if (tid < 64) {
            float s = be[tid];
#pragma unroll 8
            for (int j = 0; j < 64; j++) s += bc[j] * sWe[j * 64 + tid];
            bf[tid] = s;
        }
    }
}

// MFMA GEMM (+ fused edge-count): Y[M,128](f16) = X[M,K] @ W[K,128]
// (scaled by dinv[row] unless COUNT). COUNT mode: every block takes
// ~4 edges/thread; atomicAdds are ISSUED at kernel entry (independent of
// the GEMM) and the returned ranks COMMITTED after the epilogue — atomic
// latency and memory-side throughput hide under the GEMM's staging, MFMA
// and store phases. 512 threads, 128 rows/block; wave = 16 rows x 128
// cols (8 ct). B (fragment-major) staged once into LDS; A streamed from
// global in MFMA fragment layout (m89/m120-verified layouts).
template <int K, bool IN_F16, bool COUNT>
__global__ __launch_bounds__(512, 4) void k_gemm(const void* __restrict__ Xv,
                                                 const __half* __restrict__ Wtf,
                                                 const float* __restrict__ dinv,
                                                 __half* __restrict__ Y, int N,
                                                 const int* __restrict__ dst,
                                                 int* __restrict__ deg,
                                                 int* __restrict__ rank,
                                                 int E) {
    constexpr int NK = K / 32;
    constexpr int ITER = K / 32;  // staging sweeps: K*128*2 / (512*16)
    __shared__ __align__(16) __half sB[K * 128];

    const int tid = threadIdx.x;

    // ---- fused edge-count: issue-early ----
    int r4[4];
    int ebase = 0, estr = 0;
    if constexpr (COUNT) {
        ebase = blockIdx.x * 512 + tid;
        estr  = gridDim.x * 512;
        int d4[4];
#pragma unroll
        for (int i = 0; i < 4; ++i) {
            int e = ebase + i * estr;
            d4[i] = (e < E) ? dst[e] : 0;
        }
#pragma unroll
        for (int i = 0; i < 4; ++i) {
            int e = ebase + i * estr;
            r4[i] = (e < E) ? atomicAdd(&deg[d4[i]], 1) : 0;
        }
        // rare tail (only if E > 4*gridDim*512): immediate commit
        for (int e = ebase + 4 * estr; e < E; e += estr)
            rank[e] = atomicAdd(&deg[dst[e]], 1);
    }

    const int wv = tid >> 6, ln = tid & 63;
    const int m = ln & 15, quad = ln >> 4;
    const int rowBase = blockIdx.x * 128 + wv * 16;
    int rowA = rowBase + m;
    if (rowA > N - 1) rowA = N - 1;

    const float*  xf = (const float*)Xv;
    const __half* xh = (const __half*)Xv;
    const long aOff = (long)rowA * K + quad * 8;

    // --- issue A chunk0 (all independent, before staging) ---
    f16x8 a8[4];
    float4 t0[4], t1[4];
    if constexpr (IN_F16) {
#pragma unroll
        for (int kc = 0; kc < NK; ++kc)
            a8[kc] = *(const f16x8*)&xh[aOff + kc * 32];
    } else {
#pragma unroll
        for (int c = 0; c < 4; ++c) {
            t0[c] = *(const float4*)&xf[aOff + c * 32];
            t1[c] = *(const float4*)&xf[aOff + c * 32 + 4];
        }
    }

    // --- stage B into LDS (two-phase: all loads in flight, then writes) ---
    {
        f16x8 tb[ITER];
        const f16x8* g = (const f16x8*)Wtf;
#pragma unroll
        for (int i = 0; i < ITER; ++i) tb[i] = g[(i * 8 + wv) * 64 + ln];
        f16x8* l = (f16x8*)sB;
#pragma unroll
        for (int i = 0; i < ITER; ++i) l[(i * 8 + wv) * 64 + ln] = tb[i];
    }
    __syncthreads();

    if constexpr (!IN_F16) {
        // convert chunk0, then issue chunk1 into the freed t-registers
#pragma unroll
        for (int c = 0; c < 4; ++c) a8[c] = cvt8(t0[c], t1[c]);
#pragma unroll
        for (int c = 0; c < 4; ++c) {
            t0[c] = *(const float4*)&xf[aOff + (c + 4) * 32];
            t1[c] = *(const float4*)&xf[aOff + (c + 4) * 32 + 4];
        }
    }

    f32x4 d[8];
#pragma unroll
    for (int ct = 0; ct < 8; ++ct) d[ct] = {0.f, 0.f, 0.f, 0.f};

#pragma unroll
    for (int h = 0; h < NK / 4; ++h) {
        if constexpr (!IN_F16) {
            if (h == 1) {
#pragma unroll
                for (int c = 0; c < 4; ++c) a8[c] = cvt8(t0[c], t1[c]);
            }
        }
#pragma unroll
        for (int kq = 0; kq < 4; ++kq) {
            const int kc = h * 4 + kq;
            const f16x8 a = a8[IN_F16 ? kc : kq];
            const __half* bb = &sB[(size_t)(kc * 4 + quad) * 128 * 8];
#pragma unroll
            for (int ct = 0; ct < 8; ++ct) {
                const f16x8 b = *(const f16x8*)&bb[(ct * 16 + m) * 8];
                d[ct] = __builtin_amdgcn_mfma_f32_16x16x32_f16(a, b, d[ct], 0, 0, 0);
            }
        }
    }

#pragma unroll
    for (int ct = 0; ct < 8; ++ct) {
        const int col = ct * 16 + m;
#pragma unroll
        for (int reg = 0; reg < 4; ++reg) {
            const int row = rowBase + quad * 4 + reg;
            if (row < N) {
                if constexpr (COUNT)
                    Y[(long)row * 128 + col] = __float2half(d[ct][reg]);
                else
                    Y[(long)row * 128 + col] = __float2half(d[ct][reg] * dinv[row]);
            }
        }
    }

    // ---- fused edge-count: commit-late (ranks were in flight all along) ----
    if constexpr (COUNT) {
#pragma unroll
        for (int i = 0; i < 4; ++i) {
            int e = ebase + i * estr;
            if (e < E) rank[e] = r4[i];
        }
    }
}

// Fused classifier via MFMA (f16 input): ev(f32) = relu(H @ Wf + bf);
// evs(f16) = dinv (.) ev. B (16KB) in LDS, 512 threads, 128 rows/block,
// wave = 16 rows x 64 cols (4 ct), K=128.
__global__ __launch_bounds__(512, 4) void k_cls(const __half* __restrict__ H,
                                                const __half* __restrict__ Wtf,
                                                const float* __restrict__ bf,
                                                const float* __restrict__ dinv,
                                                float* __restrict__ ev,
                                                __half* __restrict__ evs, int N) {
    __shared__ __align__(16) __half sB[128 * 64];
    const int tid = threadIdx.x;
    const int wv = tid >> 6, ln = tid & 63;
    const int m = ln & 15, quad = ln >> 4;
    const int rowBase = blockIdx.x * 128 + wv * 16;
    int rowA = rowBase + m;
    if (rowA > N - 1) rowA = N - 1;
    const long aOff = (long)rowA * 128 + quad * 8;

    f16x8 a8[4];
#pragma unroll
    for (int kc = 0; kc < 4; ++kc)
        a8[kc] = *(const f16x8*)&H[aOff + kc * 32];

    {
        f16x8 tb[2];
        const f16x8* g = (const f16x8*)Wtf;
#pragma unroll
        for (int i = 0; i < 2; ++i) tb[i] = g[(i * 8 + wv) * 64 + ln];
        f16x8* l = (f16x8*)sB;
#pragma unroll
        for (int i = 0; i < 2; ++i) l[(i * 8 + wv) * 64 + ln] = tb[i];
    }
    __syncthreads();

    f32x4 d[4];
#pragma unroll
    for (int ct = 0; ct < 4; ++ct) d[ct] = {0.f, 0.f, 0.f, 0.f};

#pragma unroll
    for (int kc = 0; kc < 4; ++kc) {
        const __half* bb = &sB[(size_t)(kc * 4 + quad) * 64 * 8];
#pragma unroll
        for (int ct = 0; ct < 4; ++ct) {
            const f16x8 b = *(const f16x8*)&bb[(ct * 16 + m) * 8];
            d[ct] = __builtin_amdgcn_mfma_f32_16x16x32_f16(a8[kc], b, d[ct], 0, 0, 0);
        }
    }

#pragma unroll
    for (int ct = 0; ct < 4; ++ct) {
        const int col = ct * 16 + m;
#pragma unroll
        for (int reg = 0; reg < 4; ++reg) {
            const int row = rowBase + quad * 4 + reg;
            if (row < N) {
                float v = fmaxf(d[ct][reg] + bf[col], 0.f);
                ev[(long)row * 64 + col] = v;
                evs[(long)row * 64 + col] = __float2half(v * dinv[row]);
            }
        }
    }
}

// Wave-per-node gather propagation over fp16 table.
// MODE 4 (GCN, f16, unscaled tab): out = relu(di * (sum dinv[src]*tab[src]
//                                   + dinv[i]*tab[i]) + bias)
// MODE 3 (GCN, f16, prescaled tab): out = relu(di*A + bias)
// MODE 1 (APPNP inner): out(f16) = 0.9*di^2*A + 0.1*evs[i]   (scaled space)
// MODE 2 (APPNP final): out(f32) = log_softmax(0.9*di*A + 0.1*ev[i])
// csr_src indices for the NEXT group are prefetched before the current
// group's table gathers so the two dependent latencies overlap.
template <int F, int MODE>
__global__ __launch_bounds__(256) void k_prop2(const __half* __restrict__ tab,
                                               const int* __restrict__ row_ptr,
                                               const int* __restrict__ csr_src,
                                               const float* __restrict__ dinv,
                                               const float* __restrict__ bias,
                                               const void* __restrict__ evx,
                                               void* __restrict__ out, int N) {
    constexpr int LPE = F / 8;    // lanes per edge-slot (half8 = 8 feats each)
    constexpr int S = 64 / LPE;   // edge slots per wave
    int wave = threadIdx.x >> 6;
    int lane = threadIdx.x & 63;
    int node = blockIdx.x * 4 + wave;
    if (node >= N) return;
    int slot = lane / LPE;
    int fl = lane % LPE;          // features 8*fl .. 8*fl+7
    const int2 se = *(const int2*)&row_ptr[node];
    int s = se.x, e = se.y;

    float acc[8], accB[8];
#pragma unroll
    for (int q = 0; q < 8; q++) { acc[q] = 0.f; accB[q] = 0.f; }

    int j = s + slot;
    int i0 = 0, i1 = 0;
    if (j < e) i0 = csr_src[j];
    if (j + S < e) i1 = csr_src[j + S];
    while (j + S < e) {
        const int jn = j + 2 * S;
        int n0 = 0, n1 = 0;
        if (jn < e) n0 = csr_src[jn];
        if (jn + S < e) n1 = csr_src[jn + S];
        const half8 a = *(const half8*)&tab[(long)i0 * F + 8 * fl];
        const half8 b = *(const half8*)&tab[(long)i1 * F + 8 * fl];
        if (MODE == 4) {
            float da = dinv[i0], db = dinv[i1];
#pragma unroll
            for (int q = 0; q < 4; q++) {
                float2 fa = __half22float2(a.h[q]);
                float2 fb = __half22float2(b.h[q]);
                acc[2 * q] += da * fa.x; acc[2 * q + 1] += da * fa.y;
                accB[2 * q] += db * fb.x; accB[2 * q + 1] += db * fb.y;
            }
        } else {
#pragma unroll
            for (int q = 0; q < 4; q++) {
                float2 fa = __half22float2(a.h[q]);
                float2 fb = __half22float2(b.h[q]);
                acc[2 * q] += fa.x; acc[2 * q + 1] += fa.y;
                accB[2 * q] += fb.x; accB[2 * q + 1] += fb.y;
            }
        }
        i0 = n0; i1 = n1; j = jn;
    }
    if (j < e) {
        const half8 a = *(const half8*)&tab[(long)i0 * F + 8 * fl];
        if (MODE == 4) {
            float da = dinv[i0];
#pragma unroll
            for (int q = 0; q < 4; q++) {
                float2 fa = __half22float2(a.h[q]);
                acc[2 * q] += da * fa.x; acc[2 * q + 1] += da * fa.y;
            }
        } else {
#pragma unroll
            for (int q = 0; q < 4; q++) {
                float2 fa = __half22float2(a.h[q]);
                acc[2 * q] += fa.x; acc[2 * q + 1] += fa.y;
            }
        }
    }
    if (slot == 0) {  // self loop
        const half8 a = *(const half8*)&tab[(long)node * F + 8 * fl];
        float ds = (MODE == 4) ? dinv[node] : 1.f;
#pragma unroll
        for (int q = 0; q < 4; q++) {
            float2 fa = __half22float2(a.h[q]);
            acc[2 * q] += ds * fa.x; acc[2 * q + 1] += ds * fa.y;
        }
    }
#pragma unroll
    for (int q = 0; q < 8; q++) acc[q] += accB[q];

#pragma unroll
    for (int off = LPE; off < 64; off <<= 1) {
#pragma unroll
        for (int q = 0; q < 8; q++) acc[q] += __shfl_xor(acc[q], off, 64);
    }

    if (slot == 0) {
        float di = dinv[node];
        if (MODE == 3 || MODE == 4) {
            const float4 b0 = *(const float4*)&bias[8 * fl];
            const float4 b1 = *(const float4*)&bias[8 * fl + 4];
            half8 ov;
            ov.h[0] = __floats2half2_rn(fmaxf(di * acc[0] + b0.x, 0.f),
                                        fmaxf(di * acc[1] + b0.y, 0.f));
            ov.h[1] = __floats2half2_rn(fmaxf(di * acc[2] + b0.z, 0.f),
                                        fmaxf(di * acc[3] + b0.w, 0.f));
            ov.h[2] = __floats2half2_rn(fmaxf(di * acc[4] + b1.x, 0.f),
                                        fmaxf(di * acc[5] + b1.y, 0.f));
            ov.h[3] = __floats2half2_rn(fmaxf(di * acc[6] + b1.z, 0.f),
                                        fmaxf(di * acc[7] + b1.w, 0.f));
            *(half8*)&((__half*)out)[(long)node * F + 8 * fl] = ov;
        } else if (MODE == 1) {
            float d2 = 0.9f * di * di;
            const half8 eh = *(const half8*)&((const __half*)evx)[(long)node * F + 8 * fl];
            half8 ov;
#pragma unroll
            for (int q = 0; q < 4; q++) {
                float2 ef = __half22float2(eh.h[q]);
                float vx = d2 * acc[2 * q] + 0.1f * ef.x;
                float vy = d2 * acc[2 * q + 1] + 0.1f * ef.y;
                ov.h[q] = __floats2half2_rn(vx, vy);
            }
            *(half8*)&((__half*)out)[(long)node * F + 8 * fl] = ov;
        } else {
            // final APPNP step fused with log_softmax (F==64: lanes 0..7
            // of each wave hold the full 64-class row, 8 classes each)
            float d1 = 0.9f * di;
            const float* ef = (const float*)evx + (long)node * F + 8 * fl;
            const float4 e0 = *(const float4*)ef;
            const float4 e1 = *(const float4*)(ef + 4);
            float v[8];
            v[0] = d1 * acc[0] + 0.1f * e0.x;
            v[1] = d1 * acc[1] + 0.1f * e0.y;
            v[2] = d1 * acc[2] + 0.1f * e0.z;
            v[3] = d1 * acc[3] + 0.1f * e0.w;
            v[4] = d1 * acc[4] + 0.1f * e1.x;
            v[5] = d1 * acc[5] + 0.1f * e1.y;
            v[6] = d1 * acc[6] + 0.1f * e1.z;
            v[7] = d1 * acc[7] + 0.1f * e1.w;
            float m = v[0];
#pragma unroll
            for (int q = 1; q < 8; q++) m = fmaxf(m, v[q]);
#pragma unroll
            for (int off = 1; off < LPE; off <<= 1) m = fmaxf(m, __shfl_xor(m, off, 64));
            float ssum = 0.f;
#pragma unroll
            for (int q = 0; q < 8; q++) ssum += __expf(v[q] - m);
#pragma unroll
            for (int off = 1; off < LPE; off <<= 1) ssum += __shfl_xor(ssum, off, 64);
            float lse = m + __logf(ssum);
            float* o = (float*)out + (long)node * F + 8 * fl;
            float4 v0, v1;
            v0.x = v[0] - lse; v0.y = v[1] - lse; v0.z = v[2] - lse; v0.w = v[3] - lse;
            v1.x = v[4] - lse; v1.y = v[5] - lse; v1.z = v[6] - lse; v1.w = v[7] - lse;
            *(float4*)o = v0;
            *(float4*)(o + 4) = v1;
        }
    }
}

extern "C" void kernel_launch(void* const* d_in, const int* in_sizes, int n_in,
                              void* d_out, int out_size, void* d_ws, size_t ws_size,
                              hipStream_t stream) {
    const float* x  = (const float*)d_in[0];
    const int* edges = (const int*)d_in[1];
    const float* W1 = (const float*)d_in[2];
    const float* b1 = (const float*)d_in[3];
    const float* W2 = (const float*)d_in[4];
    const float* b2 = (const float*)d_in[5];
    const float* Wc = (const float*)d_in[6];
    const float* bc = (const float*)d_in[7];
    const float* We = (const float*)d_in[8];
    const float* be = (const float*)d_in[9];

    const int N = in_sizes[0] / 256;   // 100000
    const int E = in_sizes[1] / 2;     // 1600000
    const int* esrc = edges;
    const int* edst = edges + E;

    char* ws = (char*)d_ws;
    size_t off = 0;
    auto alloc = [&](size_t bytes) -> void* {
        void* p = ws + off;
        off += (bytes + 255) & ~(size_t)255;
        return p;
    };
    int*    deg     = (int*)alloc((size_t)N * 4);
    int*    row_ptr = (int*)alloc((size_t)(N + 1) * 4);
    float*  dinv    = (float*)alloc((size_t)N * 4);
    int*    bs      = (int*)alloc(4096 * 4);
    int*    rank    = (int*)alloc((size_t)E * 4);
    int*    csr_src = (int*)alloc((size_t)E * 4);
    __half* P       = (__half*)alloc((size_t)N * 128 * 2);  // f16 table A
    __half* Q16     = (__half*)alloc((size_t)N * 128 * 2);  // f16 table B
    __half* zA      = (__half*)alloc((size_t)N * 64 * 2);
    __half* zB      = (__half*)alloc((size_t)N * 64 * 2);
    __half* evs     = (__half*)alloc((size_t)N * 64 * 2);
    float*  bf      = (float*)alloc(64 * 4);
    __half* W1t     = (__half*)alloc(128 * 256 * 2);  // fragment-major
    __half* W2t     = (__half*)alloc(128 * 128 * 2);  // fragment-major
    __half* Wft     = (__half*)alloc(64 * 128 * 2);   // fragment-major
    float*  ev      = (float*)d_out;  // f32 ev lives in d_out until final step

    const int nbN = (N + 255) / 256;
    const int nbE = (E + 255) / 256;
    const int nbP = (N + 3) / 4;        // wave-per-node kernels
    const int TG  = (N + 127) / 128;    // GEMM/cls blocks (128 rows each)

    // --- prep + fat kernel: GEMM1 (unscaled) with fused edge count ---
    hipMemsetAsync(deg, 0, (size_t)N * 4, stream);
    k_prep<<<193, 256, 0, stream>>>(W1, W2, Wc, bc, We, be, W1t, W2t, Wft, bf);
    k_gemm<256, false, true><<<TG, 512, 0, stream>>>(x, W1t, nullptr, P, N,
                                                     edst, deg, rank, E);

    // --- CSR build ---
    k_scanA<<<nbN, 256, 0, stream>>>(deg, bs, N);
    k_scanB<<<1, 512, 0, stream>>>(bs, nbN);
    k_scanC<<<nbN, 256, 0, stream>>>(deg, bs, row_ptr, dinv, N);
    k_fill<<<nbE, 256, 0, stream>>>(esrc, edst, row_ptr, rank, csr_src, E);

    // --- GCN layer 1 prop (per-edge dinv: MODE 4, P unscaled) ---
    k_prop2<128, 4><<<nbP, 256, 0, stream>>>(P, row_ptr, csr_src, dinv, b1, nullptr, Q16, N);

    // --- GCN layer 2: P = f16(dinv * Q16@W2) via MFMA; Q16 = f16 relu prop ---
    k_gemm<128, true, false><<<TG, 512, 0, stream>>>(Q16, W2t, dinv, P, N,
                                                     nullptr, nullptr, nullptr, 0);
    k_prop2<128, 3><<<nbP, 256, 0, stream>>>(P, row_ptr, csr_src, dinv, b2, nullptr, Q16, N);

    // --- fused classifier (MFMA): ev (f32, d_out) + evs (f16 scaled) ---
    k_cls<<<TG, 512, 0, stream>>>(Q16, Wft, bf, dinv, ev, evs, N);

    // --- APPNP: 9 scaled f16 iterations + final step fused w/ log_softmax ---
    const __half* zin = evs;
    __half* zout;
    for (int it = 0; it < 9; ++it) {
        zout = (it % 2 == 0) ? zA : zB;
        k_prop2<64, 1><<<nbP, 256, 0, stream>>>(zin, row_ptr, csr_src, dinv, nullptr, evs, zout, N);
        zin = zout;
    }
    // final: reads zA(f16) + ev(f32,d_out), writes log_softmax rows to d_out
    k_prop2<64, 2><<<nbP, 256, 0, stream>>>(zin, row_ptr, csr_src, dinv, nullptr, ev, (float*)d_out, N);
}